// Round 2
// baseline (4769.537 us; speedup 1.0000x reference)
//
#include <hip/hip_runtime.h>
#include <cstddef>
#include <cstdint>

#define N_NODES 50000
#define N_EDGES 800000
#define F_IN 50
#define H_DIM 512
#define O_DIM 121
#define N_GROUPS 20
#define EPSV 1e-5f

#define BM 64
#define BJ 64
#define BK 16
#define STAT_SPLITS 32

typedef unsigned short u16;

__device__ __forceinline__ float b2f(u16 u) {
  union { unsigned int i; float f; } v; v.i = ((unsigned int)u) << 16; return v.f;
}
__device__ __forceinline__ u16 f2b(float f) {
  union { float f; unsigned int i; } v; v.f = f;
  unsigned int x = v.i;
  return (u16)((x + 0x7fffu + ((x >> 16) & 1u)) >> 16);  // RNE
}

// ---------------- graph preprocessing ----------------

__global__ void k_deg(const int* __restrict__ dst, int* __restrict__ deg) {
  int e = blockIdx.x * blockDim.x + threadIdx.x;
  if (e < N_EDGES) atomicAdd(&deg[dst[e]], 1);
}

// single-block inclusive scan -> exclusive offsets (N+1)
__global__ void k_scan(const int* __restrict__ deg, int* __restrict__ off) {
  __shared__ int buf[1024];
  __shared__ int carry_s;
  int tid = threadIdx.x;
  if (tid == 0) carry_s = 0;
  __syncthreads();
  for (int base = 0; base < N_NODES; base += 1024) {
    int v = (base + tid < N_NODES) ? deg[base + tid] : 0;
    buf[tid] = v;
    __syncthreads();
    for (int d = 1; d < 1024; d <<= 1) {
      int t = (tid >= d) ? buf[tid - d] : 0;
      __syncthreads();
      buf[tid] += t;
      __syncthreads();
    }
    int carry = carry_s;
    if (base + tid < N_NODES) off[base + tid + 1] = carry + buf[tid];
    __syncthreads();
    if (tid == 0) carry_s = carry + buf[1023];
    __syncthreads();
  }
  if (tid == 0) off[0] = 0;
}

// inv_deg + cursor init (after scan)
__global__ void k_prep(const int* __restrict__ deg, const int* __restrict__ csr_off,
                       float* __restrict__ inv_deg, int* __restrict__ cursor) {
  int n = blockIdx.x * blockDim.x + threadIdx.x;
  if (n < N_NODES) {
    inv_deg[n] = 1.0f / (float)max(deg[n], 1);
    cursor[n] = csr_off[n];
  }
}

__global__ void k_scatter(const int* __restrict__ src, const int* __restrict__ dst,
                          int* __restrict__ cursor, int* __restrict__ csr_src) {
  int e = blockIdx.x * blockDim.x + threadIdx.x;
  if (e < N_EDGES) {
    int p = atomicAdd(&cursor[dst[e]], 1);
    csr_src[p] = src[e];
  }
}

__global__ void k_gbounds(const int* __restrict__ batch, int* __restrict__ gstart,
                          float* __restrict__ inv_sz) {
  int g = threadIdx.x;
  if (g <= N_GROUPS) {
    int lo = 0, hi = N_NODES;
    while (lo < hi) {
      int mid = (lo + hi) >> 1;
      if (batch[mid] < g) lo = mid + 1; else hi = mid;
    }
    gstart[g] = lo;
  }
  __syncthreads();
  if (g < N_GROUPS) {
    int sz = gstart[g + 1] - gstart[g];
    inv_sz[g] = 1.0f / (float)max(sz, 1);
  }
}

// ---------------- conversions ----------------

__global__ void k_x2b(const float* __restrict__ x, u16* __restrict__ xb, int n) {
  int i = blockIdx.x * blockDim.x + threadIdx.x;
  if (i < n) xb[i] = f2b(x[i]);
}

// ---------------- aggregation ----------------

// layer 1: fp32 x in, bf16 agg out (K = F_IN = 50)
__global__ void k_agg_small(const float* __restrict__ x, const int* __restrict__ off,
                            const int* __restrict__ srcs, const float* __restrict__ inv_deg,
                            u16* __restrict__ agg) {
  int n = blockIdx.x;
  int f = threadIdx.x;
  int b = off[n], e = off[n + 1];
  if (f < F_IN) {
    float s = 0.f;
    for (int i = b; i < e; ++i) s += x[(size_t)srcs[i] * F_IN + f];
    agg[(size_t)n * F_IN + f] = f2b(s * inv_deg[n]);
  }
}

// layers 2..5: bf16 in/out, fp32 accumulate (H = 512)
__global__ __launch_bounds__(128) void k_agg512(
    const u16* __restrict__ h, const int* __restrict__ off,
    const int* __restrict__ srcs, const float* __restrict__ inv_deg,
    u16* __restrict__ agg) {
  int n = blockIdx.x;
  int t = threadIdx.x;  // 0..127, each handles 4 bf16 (8B)
  int b = off[n], e = off[n + 1];
  float a0 = 0.f, a1 = 0.f, a2 = 0.f, a3 = 0.f;
  for (int i = b; i < e; ++i) {
    ushort4 v = ((const ushort4*)(h + (size_t)srcs[i] * H_DIM))[t];
    a0 += b2f(v.x); a1 += b2f(v.y); a2 += b2f(v.z); a3 += b2f(v.w);
  }
  float w = inv_deg[n];
  ushort4 r;
  r.x = f2b(a0 * w); r.y = f2b(a1 * w); r.z = f2b(a2 * w); r.w = f2b(a3 * w);
  ((ushort4*)(agg + (size_t)n * H_DIM))[t] = r;
}

// ---------------- fused dual GEMM: C = A*Wl^T + X*Wr^T + b ----------------
// A,X: [M,K] bf16 row-major; Wl,Wr: [J,K] fp32 row-major (NT gemm)

template <bool BF16OUT>
__global__ __launch_bounds__(256) void k_gemm_fused(
    const u16* __restrict__ A, const u16* __restrict__ X,
    const float* __restrict__ Wl, const float* __restrict__ Wr,
    const float* __restrict__ bias, void* __restrict__ Cout,
    int M, int J, int K) {
  __shared__ float As[BM][BK + 1];
  __shared__ float Ws[BJ][BK + 1];
  int tid = threadIdx.x;
  int tx = tid & 15;   // J direction
  int ty = tid >> 4;   // M direction
  int m0 = blockIdx.x * BM;
  int j0 = blockIdx.y * BJ;
  int lrow = tid >> 2;
  int lcol = (tid & 3) << 2;
  float acc[4][4] = {{0.f, 0.f, 0.f, 0.f}, {0.f, 0.f, 0.f, 0.f},
                     {0.f, 0.f, 0.f, 0.f}, {0.f, 0.f, 0.f, 0.f}};
  for (int pass = 0; pass < 2; ++pass) {
    const u16* __restrict__ Ap = pass ? X : A;
    const float* __restrict__ Wp = pass ? Wr : Wl;
    for (int k0 = 0; k0 < K; k0 += BK) {
      {  // A tile (bf16)
        int m = m0 + lrow;
        float v0 = 0.f, v1 = 0.f, v2 = 0.f, v3 = 0.f;
        if (m < M) {
          const u16* p = Ap + (size_t)m * K + k0 + lcol;
          int rem = K - (k0 + lcol);
          if (rem >= 4 && ((((uintptr_t)p) & 7) == 0)) {
            ushort4 t = *(const ushort4*)p;
            v0 = b2f(t.x); v1 = b2f(t.y); v2 = b2f(t.z); v3 = b2f(t.w);
          } else {
            if (rem > 0) v0 = b2f(p[0]);
            if (rem > 1) v1 = b2f(p[1]);
            if (rem > 2) v2 = b2f(p[2]);
            if (rem > 3) v3 = b2f(p[3]);
          }
        }
        As[lrow][lcol + 0] = v0; As[lrow][lcol + 1] = v1;
        As[lrow][lcol + 2] = v2; As[lrow][lcol + 3] = v3;
      }
      {  // W tile (fp32)
        int j = j0 + lrow;
        float v0 = 0.f, v1 = 0.f, v2 = 0.f, v3 = 0.f;
        if (j < J) {
          const float* p = Wp + (size_t)j * K + k0 + lcol;
          int rem = K - (k0 + lcol);
          if (rem >= 4 && ((((uintptr_t)p) & 15) == 0)) {
            float4 t = *(const float4*)p;
            v0 = t.x; v1 = t.y; v2 = t.z; v3 = t.w;
          } else {
            if (rem > 0) v0 = p[0];
            if (rem > 1) v1 = p[1];
            if (rem > 2) v2 = p[2];
            if (rem > 3) v3 = p[3];
          }
        }
        Ws[lrow][lcol + 0] = v0; Ws[lrow][lcol + 1] = v1;
        Ws[lrow][lcol + 2] = v2; Ws[lrow][lcol + 3] = v3;
      }
      __syncthreads();
#pragma unroll
      for (int kk = 0; kk < BK; ++kk) {
        float a[4], w[4];
#pragma unroll
        for (int i = 0; i < 4; ++i) a[i] = As[ty * 4 + i][kk];
#pragma unroll
        for (int j = 0; j < 4; ++j) w[j] = Ws[tx * 4 + j][kk];
#pragma unroll
        for (int i = 0; i < 4; ++i)
#pragma unroll
          for (int j = 0; j < 4; ++j) acc[i][j] += a[i] * w[j];
      }
      __syncthreads();
    }
  }
#pragma unroll
  for (int i = 0; i < 4; ++i) {
    int m = m0 + ty * 4 + i;
    if (m >= M) continue;
#pragma unroll
    for (int j = 0; j < 4; ++j) {
      int jj = j0 + tx * 4 + j;
      if (jj < J) {
        float v = acc[i][j] + bias[jj];
        if constexpr (BF16OUT)
          ((u16*)Cout)[(size_t)m * J + jj] = f2b(v);
        else
          ((float*)Cout)[(size_t)m * J + jj] = v;
      }
    }
  }
}

// ---------------- GraphNorm ----------------

__global__ __launch_bounds__(512) void k_stats(
    const u16* __restrict__ h, const int* __restrict__ gstart,
    float* __restrict__ ssum, float* __restrict__ ssq) {
  int g = blockIdx.x;
  int sp = blockIdx.y;
  int f = threadIdx.x;
  int b = gstart[g], e = gstart[g + 1];
  int len = e - b;
  int chunk = (len + STAT_SPLITS - 1) / STAT_SPLITS;
  int lo = b + sp * chunk;
  int hi = min(lo + chunk, e);
  if (lo >= hi) return;
  float s = 0.f, q = 0.f;
  for (int n = lo; n < hi; ++n) {
    float v = b2f(h[(size_t)n * H_DIM + f]);
    s += v; q += v * v;
  }
  atomicAdd(&ssum[g * H_DIM + f], s);
  atomicAdd(&ssq[g * H_DIM + f], q);
}

__global__ void k_apply(u16* __restrict__ h, const int* __restrict__ batch,
                        const float* __restrict__ ssum, const float* __restrict__ ssq,
                        const float* __restrict__ inv_sz, const float* __restrict__ gw,
                        const float* __restrict__ gb, const float* __restrict__ alpha) {
  int idx = blockIdx.x * blockDim.x + threadIdx.x;
  if (idx >= N_NODES * H_DIM) return;
  int n = idx >> 9;
  int f = idx & (H_DIM - 1);
  int g = batch[n];
  float is = inv_sz[g];
  float m = ssum[g * H_DIM + f] * is;
  float a = alpha[f];
  float ex2 = ssq[g * H_DIM + f] * is;
  float var = ex2 - a * (2.f - a) * m * m;  // E[(x - a*m)^2]
  var = fmaxf(var, 0.f);
  float out = b2f(h[idx]) - a * m;
  float y = out * rsqrtf(var + EPSV) * gw[f] + gb[f];
  h[idx] = f2b(fmaxf(y, 0.f));
}

// ---------------- driver ----------------

extern "C" void kernel_launch(void* const* d_in, const int* in_sizes, int n_in,
                              void* d_out, int out_size, void* d_ws, size_t ws_size,
                              hipStream_t stream) {
  const float* x = (const float*)d_in[0];
  const int* edge = (const int*)d_in[1];
  const int* batch = (const int*)d_in[2];
  const float *Wl[5], *Wr[5], *bb[5];
  for (int i = 0; i < 5; ++i) {
    Wl[i] = (const float*)d_in[3 + 3 * i];
    Wr[i] = (const float*)d_in[4 + 3 * i];
    bb[i] = (const float*)d_in[5 + 3 * i];
  }
  const float *gamma[4], *beta[4], *alpha[4];
  for (int i = 0; i < 4; ++i) {
    gamma[i] = (const float*)d_in[18 + 3 * i];
    beta[i]  = (const float*)d_in[19 + 3 * i];
    alpha[i] = (const float*)d_in[20 + 3 * i];
  }
  const int* srcv = edge;
  const int* dstv = edge + N_EDGES;

  // workspace carve — total ~168 MB (bf16 activations; round 0's 311 MB fp32
  // carve is the prime suspect for the device memory fault)
  char* base = (char*)d_ws;
  size_t off = 0;
  auto carve = [&](size_t bytes) -> char* {
    char* p = base + off;
    off = (off + bytes + 255) & ~(size_t)255;
    return p;
  };
  int* deg       = (int*)carve((size_t)N_NODES * 4);
  float* inv_deg = (float*)carve((size_t)N_NODES * 4);
  int* csr_off   = (int*)carve((size_t)(N_NODES + 1) * 4);
  int* cursor    = (int*)carve((size_t)N_NODES * 4);
  int* csr_src   = (int*)carve((size_t)N_EDGES * 4);
  int* gstart    = (int*)carve((size_t)(N_GROUPS + 1) * 4);
  float* inv_sz  = (float*)carve((size_t)N_GROUPS * 4);
  float* ssum    = (float*)carve((size_t)N_GROUPS * H_DIM * 4);
  float* ssq     = (float*)carve((size_t)N_GROUPS * H_DIM * 4);
  u16* xb        = (u16*)carve((size_t)N_NODES * F_IN * 2);
  u16* aggx      = (u16*)carve((size_t)N_NODES * F_IN * 2);
  u16* h0        = (u16*)carve((size_t)N_NODES * H_DIM * 2);
  u16* h1        = (u16*)carve((size_t)N_NODES * H_DIM * 2);
  u16* h2        = (u16*)carve((size_t)N_NODES * H_DIM * 2);
  (void)ws_size; (void)in_sizes; (void)n_in; (void)out_size;

  // graph preprocessing
  hipMemsetAsync(deg, 0, (size_t)N_NODES * 4, stream);
  k_deg<<<(N_EDGES + 255) / 256, 256, 0, stream>>>(dstv, deg);
  k_scan<<<1, 1024, 0, stream>>>(deg, csr_off);
  k_prep<<<(N_NODES + 255) / 256, 256, 0, stream>>>(deg, csr_off, inv_deg, cursor);
  k_scatter<<<(N_EDGES + 255) / 256, 256, 0, stream>>>(srcv, dstv, cursor, csr_src);
  k_gbounds<<<1, 64, 0, stream>>>(batch, gstart, inv_sz);
  k_x2b<<<(N_NODES * F_IN + 255) / 256, 256, 0, stream>>>(x, xb, N_NODES * F_IN);

  dim3 gemm_grid((N_NODES + BM - 1) / BM, (H_DIM + BJ - 1) / BJ);

  auto norm = [&](u16* h, int l) {
    hipMemsetAsync(ssum, 0, (size_t)N_GROUPS * H_DIM * 4, stream);
    hipMemsetAsync(ssq, 0, (size_t)N_GROUPS * H_DIM * 4, stream);
    k_stats<<<dim3(N_GROUPS, STAT_SPLITS), 512, 0, stream>>>(h, gstart, ssum, ssq);
    k_apply<<<(N_NODES * H_DIM + 255) / 256, 256, 0, stream>>>(
        h, batch, ssum, ssq, inv_sz, gamma[l], beta[l], alpha[l]);
  };

  // layer 1 (K = F_IN = 50)
  k_agg_small<<<N_NODES, 64, 0, stream>>>(x, csr_off, csr_src, inv_deg, aggx);
  k_gemm_fused<true><<<gemm_grid, 256, 0, stream>>>(aggx, xb, Wl[0], Wr[0], bb[0], h0,
                                                    N_NODES, H_DIM, F_IN);
  norm(h0, 0);

  // layer 2
  k_agg512<<<N_NODES, 128, 0, stream>>>(h0, csr_off, csr_src, inv_deg, h1);
  k_gemm_fused<true><<<gemm_grid, 256, 0, stream>>>(h1, h0, Wl[1], Wr[1], bb[1], h2,
                                                    N_NODES, H_DIM, H_DIM);
  norm(h2, 1);

  // layer 3
  k_agg512<<<N_NODES, 128, 0, stream>>>(h2, csr_off, csr_src, inv_deg, h0);
  k_gemm_fused<true><<<gemm_grid, 256, 0, stream>>>(h0, h2, Wl[2], Wr[2], bb[2], h1,
                                                    N_NODES, H_DIM, H_DIM);
  norm(h1, 2);

  // layer 4
  k_agg512<<<N_NODES, 128, 0, stream>>>(h1, csr_off, csr_src, inv_deg, h2);
  k_gemm_fused<true><<<gemm_grid, 256, 0, stream>>>(h2, h1, Wl[3], Wr[3], bb[3], h0,
                                                    N_NODES, H_DIM, H_DIM);
  norm(h0, 3);

  // layer 5 (J = O = 121) -> d_out (fp32)
  k_agg512<<<N_NODES, 128, 0, stream>>>(h0, csr_off, csr_src, inv_deg, h1);
  dim3 gemm_grid5((N_NODES + BM - 1) / BM, (O_DIM + BJ - 1) / BJ);
  k_gemm_fused<false><<<gemm_grid5, 256, 0, stream>>>(h1, h0, Wl[4], Wr[4], bb[4],
                                                      (float*)d_out, N_NODES, O_DIM, H_DIM);
}

// Round 3
// 1571.166 us; speedup vs baseline: 3.0357x; 3.0357x over previous
//
#include <hip/hip_runtime.h>
#include <cstddef>
#include <cstdint>

#define N_NODES 50000
#define N_EDGES 800000
#define F_IN 50
#define K1PAD 64
#define H_DIM 512
#define O_DIM 121
#define O_PAD 128
#define N_GROUPS 20
#define EPSV 1e-5f
#define M_PAD 50048   // 391 * 128

#define STAT_SPLITS 32

typedef unsigned short u16;
typedef __attribute__((ext_vector_type(8))) short short8;   // 8 bf16 (4 VGPRs)
typedef __attribute__((ext_vector_type(4))) float f32x4;

__device__ __forceinline__ float b2f(u16 u) {
  union { unsigned int i; float f; } v; v.i = ((unsigned int)u) << 16; return v.f;
}
__device__ __forceinline__ u16 f2b(float f) {
  union { float f; unsigned int i; } v; v.f = f;
  unsigned int x = v.i;
  return (u16)((x + 0x7fffu + ((x >> 16) & 1u)) >> 16);  // RNE
}

__device__ __forceinline__ void gl_lds16(const void* g, void* l) {
  __builtin_amdgcn_global_load_lds(
      (__attribute__((address_space(1))) void*)(g),
      (__attribute__((address_space(3))) void*)(l), 16, 0, 0);
}

// ---------------- graph preprocessing ----------------

__global__ void k_deg(const int* __restrict__ dst, int* __restrict__ deg) {
  int e = blockIdx.x * blockDim.x + threadIdx.x;
  if (e < N_EDGES) atomicAdd(&deg[dst[e]], 1);
}

__global__ void k_scan(const int* __restrict__ deg, int* __restrict__ off) {
  __shared__ int buf[1024];
  __shared__ int carry_s;
  int tid = threadIdx.x;
  if (tid == 0) carry_s = 0;
  __syncthreads();
  for (int base = 0; base < N_NODES; base += 1024) {
    int v = (base + tid < N_NODES) ? deg[base + tid] : 0;
    buf[tid] = v;
    __syncthreads();
    for (int d = 1; d < 1024; d <<= 1) {
      int t = (tid >= d) ? buf[tid - d] : 0;
      __syncthreads();
      buf[tid] += t;
      __syncthreads();
    }
    int carry = carry_s;
    if (base + tid < N_NODES) off[base + tid + 1] = carry + buf[tid];
    __syncthreads();
    if (tid == 0) carry_s = carry + buf[1023];
    __syncthreads();
  }
  if (tid == 0) off[0] = 0;
}

__global__ void k_prep(const int* __restrict__ deg, const int* __restrict__ csr_off,
                       float* __restrict__ inv_deg, int* __restrict__ cursor) {
  int n = blockIdx.x * blockDim.x + threadIdx.x;
  if (n < N_NODES) {
    inv_deg[n] = 1.0f / (float)max(deg[n], 1);
    cursor[n] = csr_off[n];
  }
}

__global__ void k_scatter(const int* __restrict__ src, const int* __restrict__ dst,
                          int* __restrict__ cursor, int* __restrict__ csr_src) {
  int e = blockIdx.x * blockDim.x + threadIdx.x;
  if (e < N_EDGES) {
    int p = atomicAdd(&cursor[dst[e]], 1);
    csr_src[p] = src[e];
  }
}

__global__ void k_gbounds(const int* __restrict__ batch, int* __restrict__ gstart,
                          float* __restrict__ inv_sz) {
  int g = threadIdx.x;
  if (g <= N_GROUPS) {
    int lo = 0, hi = N_NODES;
    while (lo < hi) {
      int mid = (lo + hi) >> 1;
      if (batch[mid] < g) lo = mid + 1; else hi = mid;
    }
    gstart[g] = lo;
  }
  __syncthreads();
  if (g < N_GROUPS) {
    int sz = gstart[g + 1] - gstart[g];
    inv_sz[g] = 1.0f / (float)max(sz, 1);
  }
}

// ---------------- conversions ----------------

// x [N, F_IN] fp32 -> xb [M_PAD, K1PAD] bf16, zero-padded
__global__ void k_xpad(const float* __restrict__ x, u16* __restrict__ xb) {
  int i = blockIdx.x * blockDim.x + threadIdx.x;
  if (i >= M_PAD * K1PAD) return;
  int r = i >> 6, c = i & (K1PAD - 1);
  float v = (r < N_NODES && c < F_IN) ? x[r * F_IN + c] : 0.f;
  xb[i] = f2b(v);
}

// W [Jreal, Kin] fp32 -> Wb [Jp, Kp] bf16 zero-padded
__global__ void k_wconv(const float* __restrict__ W, u16* __restrict__ Wb,
                        int Jreal, int Kin, int Jp, int Kp) {
  int i = blockIdx.x * blockDim.x + threadIdx.x;
  if (i >= Jp * Kp) return;
  int j = i / Kp, k = i - j * Kp;
  float v = (j < Jreal && k < Kin) ? W[j * Kin + k] : 0.f;
  Wb[i] = f2b(v);
}

// ---------------- aggregation ----------------

// layer 1: fp32 x in, bf16 agg out [M_PAD, K1PAD] (cols >= F_IN zeroed)
__global__ void k_agg_small(const float* __restrict__ x, const int* __restrict__ off,
                            const int* __restrict__ srcs, const float* __restrict__ inv_deg,
                            u16* __restrict__ agg) {
  int n = blockIdx.x;
  int f = threadIdx.x;  // 0..63
  int b = off[n], e = off[n + 1];
  float s = 0.f;
  if (f < F_IN)
    for (int i = b; i < e; ++i) s += x[(size_t)srcs[i] * F_IN + f];
  agg[(size_t)n * K1PAD + f] = f2b(s * inv_deg[n]);
}

// layers 2..5: bf16 in/out, fp32 accumulate (H = 512)
__global__ __launch_bounds__(128) void k_agg512(
    const u16* __restrict__ h, const int* __restrict__ off,
    const int* __restrict__ srcs, const float* __restrict__ inv_deg,
    u16* __restrict__ agg) {
  int n = blockIdx.x;
  int t = threadIdx.x;
  int b = off[n], e = off[n + 1];
  float a0 = 0.f, a1 = 0.f, a2 = 0.f, a3 = 0.f;
  for (int i = b; i < e; ++i) {
    ushort4 v = ((const ushort4*)(h + (size_t)srcs[i] * H_DIM))[t];
    a0 += b2f(v.x); a1 += b2f(v.y); a2 += b2f(v.z); a3 += b2f(v.w);
  }
  float w = inv_deg[n];
  ushort4 r;
  r.x = f2b(a0 * w); r.y = f2b(a1 * w); r.z = f2b(a2 * w); r.w = f2b(a3 * w);
  ((ushort4*)(agg + (size_t)n * H_DIM))[t] = r;
}

// ---------------- MFMA dual GEMM: C = A*Wl^T + X*Wr^T + b ----------------
// A,X: [*, K] bf16 row-major (M_PAD rows); Wl,Wr: [J, K] bf16 row-major.
// 128x128 tile, BK=32, 4 waves, 16x16x32 bf16 MFMA (m97 structure).

#define TM 128
#define TN 128
#define TK 32

template <bool BF16OUT>
__global__ __launch_bounds__(256) void k_gemm_mfma(
    const u16* __restrict__ A, const u16* __restrict__ X,
    const u16* __restrict__ Wl, const u16* __restrict__ Wr,
    const float* __restrict__ bias, void* __restrict__ Cout,
    int K, int Mreal, int Jreal) {
  __shared__ u16 As[TM * TK];
  __shared__ u16 Bs[TN * TK];
  int tid = threadIdx.x;
  int lane = tid & 63;
  int wave = tid >> 6;
  int m0 = blockIdx.x * TM;
  int j0 = blockIdx.y * TN;
  int quad = lane >> 4;
  int lr = lane & 15;
  int wm = (wave & 1) * 64;
  int wn = (wave >> 1) * 64;

  f32x4 acc[4][4] = {};

  // staging: thread t loads 16 B (8 bf16); row = t/4, colgroup = t%4.
  // LDS dest = flat thread offset t*16 B -> row-major [row][32] bf16 tile
  // (global_load_lds writes wave-uniform base + lane*16 — layout matches).
  int sr = tid >> 2;
  int sc = (tid & 3) * 8;
  size_t aoff0 = (size_t)(m0 + sr) * K + sc;
  size_t aoff1 = aoff0 + (size_t)64 * K;
  size_t boff0 = (size_t)(j0 + sr) * K + sc;
  size_t boff1 = boff0 + (size_t)64 * K;
  u16* as_dst0 = As + (size_t)tid * 8;
  u16* as_dst1 = As + 2048 + (size_t)tid * 8;
  u16* bs_dst0 = Bs + (size_t)tid * 8;
  u16* bs_dst1 = Bs + 2048 + (size_t)tid * 8;

  for (int pass = 0; pass < 2; ++pass) {
    const u16* __restrict__ Ap = pass ? X : A;
    const u16* __restrict__ Wp = pass ? Wr : Wl;
    for (int k0 = 0; k0 < K; k0 += TK) {
      __syncthreads();  // previous iter's ds_reads complete before overwrite
      gl_lds16(Ap + aoff0 + k0, as_dst0);
      gl_lds16(Ap + aoff1 + k0, as_dst1);
      gl_lds16(Wp + boff0 + k0, bs_dst0);
      gl_lds16(Wp + boff1 + k0, bs_dst1);
      __syncthreads();  // compiler emits vmcnt(0) drain before s_barrier
      short8 af[4], bf[4];
#pragma unroll
      for (int t = 0; t < 4; ++t)
        af[t] = *(const short8*)(As + (wm + t * 16 + lr) * TK + quad * 8);
#pragma unroll
      for (int t = 0; t < 4; ++t)
        bf[t] = *(const short8*)(Bs + (wn + t * 16 + lr) * TK + quad * 8);
#pragma unroll
      for (int ti = 0; ti < 4; ++ti)
#pragma unroll
        for (int tj = 0; tj < 4; ++tj)
          acc[ti][tj] = __builtin_amdgcn_mfma_f32_16x16x32_bf16(
              af[ti], bf[tj], acc[ti][tj], 0, 0, 0);
    }
  }

  // epilogue: C/D layout col=lane&15, row=quad*4+reg (m89-verified)
#pragma unroll
  for (int tj = 0; tj < 4; ++tj) {
    int gcol = j0 + wn + tj * 16 + lr;
    float bv = (gcol < Jreal) ? bias[gcol] : 0.f;
#pragma unroll
    for (int ti = 0; ti < 4; ++ti) {
      f32x4 v = acc[ti][tj];
#pragma unroll
      for (int r = 0; r < 4; ++r) {
        int grow = m0 + wm + ti * 16 + quad * 4 + r;
        if (grow < Mreal && gcol < Jreal) {
          float val = v[r] + bv;
          if constexpr (BF16OUT)
            ((u16*)Cout)[(size_t)grow * Jreal + gcol] = f2b(val);
          else
            ((float*)Cout)[(size_t)grow * Jreal + gcol] = val;
        }
      }
    }
  }
}

// ---------------- GraphNorm ----------------

__global__ __launch_bounds__(512) void k_stats(
    const u16* __restrict__ h, const int* __restrict__ gstart,
    float* __restrict__ ssum, float* __restrict__ ssq) {
  int g = blockIdx.x;
  int sp = blockIdx.y;
  int f = threadIdx.x;
  int b = gstart[g], e = gstart[g + 1];
  int len = e - b;
  int chunk = (len + STAT_SPLITS - 1) / STAT_SPLITS;
  int lo = b + sp * chunk;
  int hi = min(lo + chunk, e);
  if (lo >= hi) return;
  float s = 0.f, q = 0.f;
  for (int n = lo; n < hi; ++n) {
    float v = b2f(h[(size_t)n * H_DIM + f]);
    s += v; q += v * v;
  }
  atomicAdd(&ssum[g * H_DIM + f], s);
  atomicAdd(&ssq[g * H_DIM + f], q);
}

__global__ void k_apply(u16* __restrict__ h, const int* __restrict__ batch,
                        const float* __restrict__ ssum, const float* __restrict__ ssq,
                        const float* __restrict__ inv_sz, const float* __restrict__ gw,
                        const float* __restrict__ gb, const float* __restrict__ alpha) {
  int idx = blockIdx.x * blockDim.x + threadIdx.x;
  if (idx >= N_NODES * H_DIM) return;
  int n = idx >> 9;
  int f = idx & (H_DIM - 1);
  int g = batch[n];
  float is = inv_sz[g];
  float m = ssum[g * H_DIM + f] * is;
  float a = alpha[f];
  float ex2 = ssq[g * H_DIM + f] * is;
  float var = ex2 - a * (2.f - a) * m * m;  // E[(x - a*m)^2]
  var = fmaxf(var, 0.f);
  float out = b2f(h[idx]) - a * m;
  float y = out * rsqrtf(var + EPSV) * gw[f] + gb[f];
  h[idx] = f2b(fmaxf(y, 0.f));
}

// ---------------- driver ----------------

extern "C" void kernel_launch(void* const* d_in, const int* in_sizes, int n_in,
                              void* d_out, int out_size, void* d_ws, size_t ws_size,
                              hipStream_t stream) {
  const float* x = (const float*)d_in[0];
  const int* edge = (const int*)d_in[1];
  const int* batch = (const int*)d_in[2];
  const float *Wl[5], *Wr[5], *bb[5];
  for (int i = 0; i < 5; ++i) {
    Wl[i] = (const float*)d_in[3 + 3 * i];
    Wr[i] = (const float*)d_in[4 + 3 * i];
    bb[i] = (const float*)d_in[5 + 3 * i];
  }
  const float *gamma[4], *beta[4], *alpha[4];
  for (int i = 0; i < 4; ++i) {
    gamma[i] = (const float*)d_in[18 + 3 * i];
    beta[i]  = (const float*)d_in[19 + 3 * i];
    alpha[i] = (const float*)d_in[20 + 3 * i];
  }
  const int* srcv = edge;
  const int* dstv = edge + N_EDGES;

  char* base = (char*)d_ws;
  size_t off = 0;
  auto carve = [&](size_t bytes) -> char* {
    char* p = base + off;
    off = (off + bytes + 255) & ~(size_t)255;
    return p;
  };
  int* deg       = (int*)carve((size_t)N_NODES * 4);
  float* inv_deg = (float*)carve((size_t)N_NODES * 4);
  int* csr_off   = (int*)carve((size_t)(N_NODES + 1) * 4);
  int* cursor    = (int*)carve((size_t)N_NODES * 4);
  int* csr_src   = (int*)carve((size_t)N_EDGES * 4);
  int* gstart    = (int*)carve((size_t)(N_GROUPS + 1) * 4);
  float* inv_sz  = (float*)carve((size_t)N_GROUPS * 4);
  float* ssum    = (float*)carve((size_t)N_GROUPS * H_DIM * 4);
  float* ssq     = (float*)carve((size_t)N_GROUPS * H_DIM * 4);
  u16* xb        = (u16*)carve((size_t)M_PAD * K1PAD * 2);
  u16* aggx      = (u16*)carve((size_t)M_PAD * K1PAD * 2);
  u16* h0        = (u16*)carve((size_t)M_PAD * H_DIM * 2);
  u16* h1        = (u16*)carve((size_t)M_PAD * H_DIM * 2);
  u16* h2        = (u16*)carve((size_t)M_PAD * H_DIM * 2);
  u16* w1lb = (u16*)carve((size_t)H_DIM * K1PAD * 2);
  u16* w1rb = (u16*)carve((size_t)H_DIM * K1PAD * 2);
  u16* w2lb = (u16*)carve((size_t)H_DIM * H_DIM * 2);
  u16* w2rb = (u16*)carve((size_t)H_DIM * H_DIM * 2);
  u16* w3lb = (u16*)carve((size_t)H_DIM * H_DIM * 2);
  u16* w3rb = (u16*)carve((size_t)H_DIM * H_DIM * 2);
  u16* w4lb = (u16*)carve((size_t)H_DIM * H_DIM * 2);
  u16* w4rb = (u16*)carve((size_t)H_DIM * H_DIM * 2);
  u16* w5lb = (u16*)carve((size_t)O_PAD * H_DIM * 2);
  u16* w5rb = (u16*)carve((size_t)O_PAD * H_DIM * 2);
  (void)ws_size; (void)in_sizes; (void)n_in; (void)out_size;

  // graph preprocessing
  hipMemsetAsync(deg, 0, (size_t)N_NODES * 4, stream);
  k_deg<<<(N_EDGES + 255) / 256, 256, 0, stream>>>(dstv, deg);
  k_scan<<<1, 1024, 0, stream>>>(deg, csr_off);
  k_prep<<<(N_NODES + 255) / 256, 256, 0, stream>>>(deg, csr_off, inv_deg, cursor);
  k_scatter<<<(N_EDGES + 255) / 256, 256, 0, stream>>>(srcv, dstv, cursor, csr_src);
  k_gbounds<<<1, 64, 0, stream>>>(batch, gstart, inv_sz);
  k_xpad<<<(M_PAD * K1PAD + 255) / 256, 256, 0, stream>>>(x, xb);

  // weight conversion (fp32 -> padded bf16)
  auto wconv = [&](const float* W, u16* Wb, int Jr, int Kin, int Jp, int Kp) {
    k_wconv<<<(Jp * Kp + 255) / 256, 256, 0, stream>>>(W, Wb, Jr, Kin, Jp, Kp);
  };
  wconv(Wl[0], w1lb, H_DIM, F_IN, H_DIM, K1PAD);
  wconv(Wr[0], w1rb, H_DIM, F_IN, H_DIM, K1PAD);
  wconv(Wl[1], w2lb, H_DIM, H_DIM, H_DIM, H_DIM);
  wconv(Wr[1], w2rb, H_DIM, H_DIM, H_DIM, H_DIM);
  wconv(Wl[2], w3lb, H_DIM, H_DIM, H_DIM, H_DIM);
  wconv(Wr[2], w3rb, H_DIM, H_DIM, H_DIM, H_DIM);
  wconv(Wl[3], w4lb, H_DIM, H_DIM, H_DIM, H_DIM);
  wconv(Wr[3], w4rb, H_DIM, H_DIM, H_DIM, H_DIM);
  wconv(Wl[4], w5lb, O_DIM, H_DIM, O_PAD, H_DIM);
  wconv(Wr[4], w5rb, O_DIM, H_DIM, O_PAD, H_DIM);

  dim3 ggrid(M_PAD / TM, H_DIM / TN);   // (391, 4)
  dim3 ggrid5(M_PAD / TM, O_PAD / TN);  // (391, 1)

  auto norm = [&](u16* h, int l) {
    hipMemsetAsync(ssum, 0, (size_t)N_GROUPS * H_DIM * 4, stream);
    hipMemsetAsync(ssq, 0, (size_t)N_GROUPS * H_DIM * 4, stream);
    k_stats<<<dim3(N_GROUPS, STAT_SPLITS), 512, 0, stream>>>(h, gstart, ssum, ssq);
    k_apply<<<(N_NODES * H_DIM + 255) / 256, 256, 0, stream>>>(
        h, batch, ssum, ssq, inv_sz, gamma[l], beta[l], alpha[l]);
  };

  // layer 1 (K = 64 padded)
  k_agg_small<<<N_NODES, 64, 0, stream>>>(x, csr_off, csr_src, inv_deg, aggx);
  k_gemm_mfma<true><<<ggrid, 256, 0, stream>>>(aggx, xb, w1lb, w1rb, bb[0], h0,
                                               K1PAD, M_PAD, H_DIM);
  norm(h0, 0);

  // layer 2
  k_agg512<<<N_NODES, 128, 0, stream>>>(h0, csr_off, csr_src, inv_deg, h1);
  k_gemm_mfma<true><<<ggrid, 256, 0, stream>>>(h1, h0, w2lb, w2rb, bb[1], h2,
                                               H_DIM, M_PAD, H_DIM);
  norm(h2, 1);

  // layer 3
  k_agg512<<<N_NODES, 128, 0, stream>>>(h2, csr_off, csr_src, inv_deg, h0);
  k_gemm_mfma<true><<<ggrid, 256, 0, stream>>>(h0, h2, w3lb, w3rb, bb[2], h1,
                                               H_DIM, M_PAD, H_DIM);
  norm(h1, 2);

  // layer 4
  k_agg512<<<N_NODES, 128, 0, stream>>>(h1, csr_off, csr_src, inv_deg, h2);
  k_gemm_mfma<true><<<ggrid, 256, 0, stream>>>(h2, h1, w4lb, w4rb, bb[3], h0,
                                               H_DIM, M_PAD, H_DIM);
  norm(h0, 3);

  // layer 5 (J = 121, padded weights to 128) -> d_out fp32
  k_agg512<<<N_NODES, 128, 0, stream>>>(h0, csr_off, csr_src, inv_deg, h1);
  k_gemm_mfma<false><<<ggrid5, 256, 0, stream>>>(h1, h0, w5lb, w5rb, bb[4],
                                                 (float*)d_out, H_DIM, N_NODES, O_DIM);
}

// Round 4
// 1461.967 us; speedup vs baseline: 3.2624x; 1.0747x over previous
//
#include <hip/hip_runtime.h>
#include <cstddef>
#include <cstdint>

#define N_NODES 50000
#define N_EDGES 800000
#define F_IN 50
#define K1PAD 64
#define H_DIM 512
#define O_DIM 121
#define O_PAD 128
#define N_GROUPS 20
#define EPSV 1e-5f
#define M_PAD 50048   // 391 * 128

#define STAT_SPLITS 32
#define SCAN_BLK 256
#define SCAN_NBLK ((N_NODES + SCAN_BLK - 1) / SCAN_BLK)  // 196

typedef unsigned short u16;
typedef __attribute__((ext_vector_type(8))) short short8;          // 8 bf16 (4 VGPRs)
typedef __attribute__((ext_vector_type(8))) unsigned short u16x8;  // 16B vector load
typedef __attribute__((ext_vector_type(4))) float f32x4;

__device__ __forceinline__ float b2f(u16 u) {
  union { unsigned int i; float f; } v; v.i = ((unsigned int)u) << 16; return v.f;
}
__device__ __forceinline__ u16 f2b(float f) {
  union { float f; unsigned int i; } v; v.f = f;
  unsigned int x = v.i;
  return (u16)((x + 0x7fffu + ((x >> 16) & 1u)) >> 16);  // RNE
}

__device__ __forceinline__ void gl_lds16(const void* g, void* l) {
  __builtin_amdgcn_global_load_lds(
      (__attribute__((address_space(1))) void*)(g),
      (__attribute__((address_space(3))) void*)(l), 16, 0, 0);
}

// ---------------- graph preprocessing ----------------

__global__ void k_deg(const int* __restrict__ dst, int* __restrict__ deg) {
  int e = blockIdx.x * blockDim.x + threadIdx.x;
  if (e < N_EDGES) atomicAdd(&deg[dst[e]], 1);
}

// 3-kernel scan: per-block inclusive -> scan block sums -> add offsets
__global__ void k_scan1(const int* __restrict__ deg, int* __restrict__ off,
                        int* __restrict__ bsum) {
  __shared__ int buf[SCAN_BLK];
  int gid = blockIdx.x * SCAN_BLK + threadIdx.x;
  buf[threadIdx.x] = (gid < N_NODES) ? deg[gid] : 0;
  __syncthreads();
  for (int d = 1; d < SCAN_BLK; d <<= 1) {
    int t = (threadIdx.x >= d) ? buf[threadIdx.x - d] : 0;
    __syncthreads();
    buf[threadIdx.x] += t;
    __syncthreads();
  }
  if (gid < N_NODES) off[gid + 1] = buf[threadIdx.x];
  if (threadIdx.x == SCAN_BLK - 1) bsum[blockIdx.x] = buf[threadIdx.x];
}

__global__ void k_scan2(int* __restrict__ bsum) {
  __shared__ int buf[256];
  int t = threadIdx.x;
  buf[t] = (t < SCAN_NBLK) ? bsum[t] : 0;
  __syncthreads();
  for (int d = 1; d < 256; d <<= 1) {
    int v = (t >= d) ? buf[t - d] : 0;
    __syncthreads();
    buf[t] += v;
    __syncthreads();
  }
  if (t < SCAN_NBLK) bsum[t] = buf[t];
}

__global__ void k_scan3(int* __restrict__ off, const int* __restrict__ bsum) {
  int gid = blockIdx.x * SCAN_BLK + threadIdx.x;
  if (gid < N_NODES) {
    int add = (blockIdx.x > 0) ? bsum[blockIdx.x - 1] : 0;
    off[gid + 1] += add;
  }
  if (gid == 0) off[0] = 0;
}

__global__ void k_prep(const int* __restrict__ deg, const int* __restrict__ csr_off,
                       float* __restrict__ inv_deg, int* __restrict__ cursor) {
  int n = blockIdx.x * blockDim.x + threadIdx.x;
  if (n < N_NODES) {
    inv_deg[n] = 1.0f / (float)max(deg[n], 1);
    cursor[n] = csr_off[n];
  }
}

__global__ void k_scatter(const int* __restrict__ src, const int* __restrict__ dst,
                          int* __restrict__ cursor, int* __restrict__ csr_src) {
  int e = blockIdx.x * blockDim.x + threadIdx.x;
  if (e < N_EDGES) {
    int p = atomicAdd(&cursor[dst[e]], 1);
    csr_src[p] = src[e];
  }
}

__global__ void k_gbounds(const int* __restrict__ batch, int* __restrict__ gstart,
                          float* __restrict__ inv_sz) {
  int g = threadIdx.x;
  if (g <= N_GROUPS) {
    int lo = 0, hi = N_NODES;
    while (lo < hi) {
      int mid = (lo + hi) >> 1;
      if (batch[mid] < g) lo = mid + 1; else hi = mid;
    }
    gstart[g] = lo;
  }
  __syncthreads();
  if (g < N_GROUPS) {
    int sz = gstart[g + 1] - gstart[g];
    inv_sz[g] = 1.0f / (float)max(sz, 1);
  }
}

// ---------------- conversions ----------------

__global__ void k_xpad(const float* __restrict__ x, u16* __restrict__ xb) {
  int i = blockIdx.x * blockDim.x + threadIdx.x;
  if (i >= M_PAD * K1PAD) return;
  int r = i >> 6, c = i & (K1PAD - 1);
  float v = (r < N_NODES && c < F_IN) ? x[r * F_IN + c] : 0.f;
  xb[i] = f2b(v);
}

__global__ void k_wconv(const float* __restrict__ W, u16* __restrict__ Wb,
                        int Jreal, int Kin, int Jp, int Kp) {
  int i = blockIdx.x * blockDim.x + threadIdx.x;
  if (i >= Jp * Kp) return;
  int j = i / Kp, k = i - j * Kp;
  float v = (j < Jreal && k < Kin) ? W[j * Kin + k] : 0.f;
  Wb[i] = f2b(v);
}

// ---------------- aggregation ----------------

// layer 1: fp32 x in, bf16 agg out [*, K1PAD] (cols >= F_IN zeroed)
__global__ void k_agg_small(const float* __restrict__ x, const int* __restrict__ off,
                            const int* __restrict__ srcs, const float* __restrict__ inv_deg,
                            u16* __restrict__ agg) {
  int n = blockIdx.x;
  int f = threadIdx.x;  // 0..63
  int b = off[n], e = off[n + 1];
  float s = 0.f;
  if (f < F_IN)
    for (int i = b; i < e; ++i) s += x[(size_t)srcs[i] * F_IN + f];
  agg[(size_t)n * K1PAD + f] = f2b(s * inv_deg[n]);
}

// layers 2..5: 16B loads, one wave per node, 4 nodes per block
__global__ __launch_bounds__(256) void k_agg512(
    const u16* __restrict__ h, const int* __restrict__ off,
    const int* __restrict__ srcs, const float* __restrict__ inv_deg,
    u16* __restrict__ agg) {
  int n = blockIdx.x * 4 + threadIdx.y;
  if (n >= N_NODES) return;
  int t = threadIdx.x;  // 0..63, 8 bf16 (16B) per lane covers a 512-col row
  int b = off[n], e = off[n + 1];
  float a[8] = {0.f, 0.f, 0.f, 0.f, 0.f, 0.f, 0.f, 0.f};
  int i = b;
  for (; i + 2 <= e; i += 2) {
    int s0 = srcs[i], s1 = srcs[i + 1];
    u16x8 v0 = ((const u16x8*)(h + (size_t)s0 * H_DIM))[t];
    u16x8 v1 = ((const u16x8*)(h + (size_t)s1 * H_DIM))[t];
#pragma unroll
    for (int j = 0; j < 8; ++j) a[j] += b2f(v0[j]) + b2f(v1[j]);
  }
  if (i < e) {
    u16x8 v0 = ((const u16x8*)(h + (size_t)srcs[i] * H_DIM))[t];
#pragma unroll
    for (int j = 0; j < 8; ++j) a[j] += b2f(v0[j]);
  }
  float w = inv_deg[n];
  u16x8 r;
#pragma unroll
  for (int j = 0; j < 8; ++j) r[j] = f2b(a[j] * w);
  ((u16x8*)(agg + (size_t)n * H_DIM))[t] = r;
}

// ---------------- MFMA fused dual GEMM: C = A*Wl^T + X*Wr^T + b -------------
// Single K-loop stages all 4 tiles (A, X, Wl, Wr): 32 MFMAs per barrier pair.
// grid = (J/TN, M/TM): j fastest -> consecutive blocks share the A/X m-tile
// (HBM fetch once, L2/L3 reuse across the 4 j-tiles).

#define TM 128
#define TN 128
#define TK 32

template <bool BF16OUT>
__global__ __launch_bounds__(256) void k_gemm_mfma(
    const u16* __restrict__ A, const u16* __restrict__ X,
    const u16* __restrict__ Wl, const u16* __restrict__ Wr,
    const float* __restrict__ bias, void* __restrict__ Cout,
    int K, int Mreal, int Jreal) {
  __shared__ u16 As[TM * TK];
  __shared__ u16 Xs[TM * TK];
  __shared__ u16 Ls[TN * TK];
  __shared__ u16 Rs[TN * TK];
  int tid = threadIdx.x;
  int lane = tid & 63;
  int wave = tid >> 6;
  int j0 = blockIdx.x * TN;
  int m0 = blockIdx.y * TM;
  int quad = lane >> 4;
  int lr = lane & 15;
  int wm = (wave & 1) * 64;
  int wn = (wave >> 1) * 64;

  f32x4 acc[4][4] = {};

  // staging: thread t loads 16B; row = t/4, colgroup = t%4 -> row-major [64][32]
  int sr = tid >> 2;
  int sc = (tid & 3) * 8;
  size_t moff0 = (size_t)(m0 + sr) * K + sc;
  size_t moff1 = moff0 + (size_t)64 * K;
  size_t joff0 = (size_t)(j0 + sr) * K + sc;
  size_t joff1 = joff0 + (size_t)64 * K;
  const int dofs = tid * 8;

  for (int k0 = 0; k0 < K; k0 += TK) {
    __syncthreads();
    gl_lds16(A + moff0 + k0, As + dofs);
    gl_lds16(A + moff1 + k0, As + 2048 + dofs);
    gl_lds16(X + moff0 + k0, Xs + dofs);
    gl_lds16(X + moff1 + k0, Xs + 2048 + dofs);
    gl_lds16(Wl + joff0 + k0, Ls + dofs);
    gl_lds16(Wl + joff1 + k0, Ls + 2048 + dofs);
    gl_lds16(Wr + joff0 + k0, Rs + dofs);
    gl_lds16(Wr + joff1 + k0, Rs + 2048 + dofs);
    __syncthreads();
    short8 af[4], xf[4], lf[4], rf[4];
#pragma unroll
    for (int t = 0; t < 4; ++t) {
      int row = (wm + t * 16 + lr) * TK + quad * 8;
      af[t] = *(const short8*)(As + row);
      xf[t] = *(const short8*)(Xs + row);
    }
#pragma unroll
    for (int t = 0; t < 4; ++t) {
      int row = (wn + t * 16 + lr) * TK + quad * 8;
      lf[t] = *(const short8*)(Ls + row);
      rf[t] = *(const short8*)(Rs + row);
    }
#pragma unroll
    for (int ti = 0; ti < 4; ++ti)
#pragma unroll
      for (int tj = 0; tj < 4; ++tj) {
        acc[ti][tj] = __builtin_amdgcn_mfma_f32_16x16x32_bf16(
            af[ti], lf[tj], acc[ti][tj], 0, 0, 0);
        acc[ti][tj] = __builtin_amdgcn_mfma_f32_16x16x32_bf16(
            xf[ti], rf[tj], acc[ti][tj], 0, 0, 0);
      }
  }

  // epilogue: C/D layout col=lane&15, row=quad*4+reg (m89-verified)
#pragma unroll
  for (int tj = 0; tj < 4; ++tj) {
    int gcol = j0 + wn + tj * 16 + lr;
    float bv = (gcol < Jreal) ? bias[gcol] : 0.f;
#pragma unroll
    for (int ti = 0; ti < 4; ++ti) {
      f32x4 v = acc[ti][tj];
#pragma unroll
      for (int r = 0; r < 4; ++r) {
        int grow = m0 + wm + ti * 16 + quad * 4 + r;
        if (grow < Mreal && gcol < Jreal) {
          float val = v[r] + bv;
          if constexpr (BF16OUT)
            ((u16*)Cout)[(size_t)grow * Jreal + gcol] = f2b(val);
          else
            ((float*)Cout)[(size_t)grow * Jreal + gcol] = val;
        }
      }
    }
  }
}

// ---------------- GraphNorm ----------------

__global__ __launch_bounds__(512) void k_stats(
    const u16* __restrict__ h, const int* __restrict__ gstart,
    float* __restrict__ ssum, float* __restrict__ ssq) {
  int g = blockIdx.x;
  int sp = blockIdx.y;
  int f = threadIdx.x;
  int b = gstart[g], e = gstart[g + 1];
  int len = e - b;
  int chunk = (len + STAT_SPLITS - 1) / STAT_SPLITS;
  int lo = b + sp * chunk;
  int hi = min(lo + chunk, e);
  if (lo >= hi) return;
  float s = 0.f, q = 0.f;
  for (int n = lo; n < hi; ++n) {
    float v = b2f(h[(size_t)n * H_DIM + f]);
    s += v; q += v * v;
  }
  atomicAdd(&ssum[g * H_DIM + f], s);
  atomicAdd(&ssq[g * H_DIM + f], q);
}

__global__ void k_apply(u16* __restrict__ h, const int* __restrict__ batch,
                        const float* __restrict__ ssum, const float* __restrict__ ssq,
                        const float* __restrict__ inv_sz, const float* __restrict__ gw,
                        const float* __restrict__ gb, const float* __restrict__ alpha) {
  int idx = blockIdx.x * blockDim.x + threadIdx.x;
  if (idx >= N_NODES * H_DIM) return;
  int n = idx >> 9;
  int f = idx & (H_DIM - 1);
  int g = batch[n];
  float is = inv_sz[g];
  float m = ssum[g * H_DIM + f] * is;
  float a = alpha[f];
  float ex2 = ssq[g * H_DIM + f] * is;
  float var = ex2 - a * (2.f - a) * m * m;  // E[(x - a*m)^2]
  var = fmaxf(var, 0.f);
  float out = b2f(h[idx]) - a * m;
  float y = out * rsqrtf(var + EPSV) * gw[f] + gb[f];
  h[idx] = f2b(fmaxf(y, 0.f));
}

// ---------------- driver ----------------

extern "C" void kernel_launch(void* const* d_in, const int* in_sizes, int n_in,
                              void* d_out, int out_size, void* d_ws, size_t ws_size,
                              hipStream_t stream) {
  const float* x = (const float*)d_in[0];
  const int* edge = (const int*)d_in[1];
  const int* batch = (const int*)d_in[2];
  const float *Wl[5], *Wr[5], *bb[5];
  for (int i = 0; i < 5; ++i) {
    Wl[i] = (const float*)d_in[3 + 3 * i];
    Wr[i] = (const float*)d_in[4 + 3 * i];
    bb[i] = (const float*)d_in[5 + 3 * i];
  }
  const float *gamma[4], *beta[4], *alpha[4];
  for (int i = 0; i < 4; ++i) {
    gamma[i] = (const float*)d_in[18 + 3 * i];
    beta[i]  = (const float*)d_in[19 + 3 * i];
    alpha[i] = (const float*)d_in[20 + 3 * i];
  }
  const int* srcv = edge;
  const int* dstv = edge + N_EDGES;

  char* base = (char*)d_ws;
  size_t off = 0;
  auto carve = [&](size_t bytes) -> char* {
    char* p = base + off;
    off = (off + bytes + 255) & ~(size_t)255;
    return p;
  };
  int* deg       = (int*)carve((size_t)N_NODES * 4);
  float* inv_deg = (float*)carve((size_t)N_NODES * 4);
  int* csr_off   = (int*)carve((size_t)(N_NODES + 1) * 4);
  int* cursor    = (int*)carve((size_t)N_NODES * 4);
  int* csr_src   = (int*)carve((size_t)N_EDGES * 4);
  int* bsum      = (int*)carve((size_t)SCAN_NBLK * 4);
  int* gstart    = (int*)carve((size_t)(N_GROUPS + 1) * 4);
  float* inv_sz  = (float*)carve((size_t)N_GROUPS * 4);
  float* ssum    = (float*)carve((size_t)N_GROUPS * H_DIM * 4);  // contiguous with ssq
  float* ssq     = (float*)carve((size_t)N_GROUPS * H_DIM * 4);
  u16* xb        = (u16*)carve((size_t)M_PAD * K1PAD * 2);
  u16* aggx      = (u16*)carve((size_t)M_PAD * K1PAD * 2);
  u16* h0        = (u16*)carve((size_t)M_PAD * H_DIM * 2);
  u16* h1        = (u16*)carve((size_t)M_PAD * H_DIM * 2);
  u16* h2        = (u16*)carve((size_t)M_PAD * H_DIM * 2);
  u16* w1lb = (u16*)carve((size_t)H_DIM * K1PAD * 2);
  u16* w1rb = (u16*)carve((size_t)H_DIM * K1PAD * 2);
  u16* w2lb = (u16*)carve((size_t)H_DIM * H_DIM * 2);
  u16* w2rb = (u16*)carve((size_t)H_DIM * H_DIM * 2);
  u16* w3lb = (u16*)carve((size_t)H_DIM * H_DIM * 2);
  u16* w3rb = (u16*)carve((size_t)H_DIM * H_DIM * 2);
  u16* w4lb = (u16*)carve((size_t)H_DIM * H_DIM * 2);
  u16* w4rb = (u16*)carve((size_t)H_DIM * H_DIM * 2);
  u16* w5lb = (u16*)carve((size_t)O_PAD * H_DIM * 2);
  u16* w5rb = (u16*)carve((size_t)O_PAD * H_DIM * 2);
  (void)ws_size; (void)in_sizes; (void)n_in; (void)out_size;

  // graph preprocessing
  hipMemsetAsync(deg, 0, (size_t)N_NODES * 4, stream);
  k_deg<<<(N_EDGES + 255) / 256, 256, 0, stream>>>(dstv, deg);
  k_scan1<<<SCAN_NBLK, SCAN_BLK, 0, stream>>>(deg, csr_off, bsum);
  k_scan2<<<1, 256, 0, stream>>>(bsum);
  k_scan3<<<SCAN_NBLK, SCAN_BLK, 0, stream>>>(csr_off, bsum);
  k_prep<<<(N_NODES + 255) / 256, 256, 0, stream>>>(deg, csr_off, inv_deg, cursor);
  k_scatter<<<(N_EDGES + 255) / 256, 256, 0, stream>>>(srcv, dstv, cursor, csr_src);
  k_gbounds<<<1, 64, 0, stream>>>(batch, gstart, inv_sz);
  k_xpad<<<(M_PAD * K1PAD + 255) / 256, 256, 0, stream>>>(x, xb);

  auto wconv = [&](const float* W, u16* Wb, int Jr, int Kin, int Jp, int Kp) {
    k_wconv<<<(Jp * Kp + 255) / 256, 256, 0, stream>>>(W, Wb, Jr, Kin, Jp, Kp);
  };
  wconv(Wl[0], w1lb, H_DIM, F_IN, H_DIM, K1PAD);
  wconv(Wr[0], w1rb, H_DIM, F_IN, H_DIM, K1PAD);
  wconv(Wl[1], w2lb, H_DIM, H_DIM, H_DIM, H_DIM);
  wconv(Wr[1], w2rb, H_DIM, H_DIM, H_DIM, H_DIM);
  wconv(Wl[2], w3lb, H_DIM, H_DIM, H_DIM, H_DIM);
  wconv(Wr[2], w3rb, H_DIM, H_DIM, H_DIM, H_DIM);
  wconv(Wl[3], w4lb, H_DIM, H_DIM, H_DIM, H_DIM);
  wconv(Wr[3], w4rb, H_DIM, H_DIM, H_DIM, H_DIM);
  wconv(Wl[4], w5lb, O_DIM, H_DIM, O_PAD, H_DIM);
  wconv(Wr[4], w5rb, O_DIM, H_DIM, O_PAD, H_DIM);

  dim3 ggrid(H_DIM / TN, M_PAD / TM);   // (4, 391) — j fastest
  dim3 ggrid5(O_PAD / TN, M_PAD / TM);  // (1, 391)
  dim3 aggblk(64, 4);
  int aggrid = (N_NODES + 3) / 4;

  auto norm = [&](u16* h, int l) {
    hipMemsetAsync(ssum, 0, (size_t)N_GROUPS * H_DIM * 4 * 2, stream);  // ssum+ssq
    k_stats<<<dim3(N_GROUPS, STAT_SPLITS), 512, 0, stream>>>(h, gstart, ssum, ssq);
    k_apply<<<(N_NODES * H_DIM + 255) / 256, 256, 0, stream>>>(
        h, batch, ssum, ssq, inv_sz, gamma[l], beta[l], alpha[l]);
  };

  // layer 1 (K = 64 padded)
  k_agg_small<<<N_NODES, 64, 0, stream>>>(x, csr_off, csr_src, inv_deg, aggx);
  k_gemm_mfma<true><<<ggrid, 256, 0, stream>>>(aggx, xb, w1lb, w1rb, bb[0], h0,
                                               K1PAD, M_PAD, H_DIM);
  norm(h0, 0);

  // layer 2
  k_agg512<<<aggrid, aggblk, 0, stream>>>(h0, csr_off, csr_src, inv_deg, h1);
  k_gemm_mfma<true><<<ggrid, 256, 0, stream>>>(h1, h0, w2lb, w2rb, bb[1], h2,
                                               H_DIM, M_PAD, H_DIM);
  norm(h2, 1);

  // layer 3
  k_agg512<<<aggrid, aggblk, 0, stream>>>(h2, csr_off, csr_src, inv_deg, h0);
  k_gemm_mfma<true><<<ggrid, 256, 0, stream>>>(h0, h2, w3lb, w3rb, bb[2], h1,
                                               H_DIM, M_PAD, H_DIM);
  norm(h1, 2);

  // layer 4
  k_agg512<<<aggrid, aggblk, 0, stream>>>(h1, csr_off, csr_src, inv_deg, h2);
  k_gemm_mfma<true><<<ggrid, 256, 0, stream>>>(h2, h1, w4lb, w4rb, bb[3], h0,
                                               H_DIM, M_PAD, H_DIM);
  norm(h0, 3);

  // layer 5 (J = 121, padded weights to 128) -> d_out fp32
  k_agg512<<<aggrid, aggblk, 0, stream>>>(h0, csr_off, csr_src, inv_deg, h1);
  k_gemm_mfma<false><<<ggrid5, 256, 0, stream>>>(h1, h0, w5lb, w5rb, bb[4],
                                                 (float*)d_out, H_DIM, N_NODES, O_DIM);
}

// Round 5
// 1363.143 us; speedup vs baseline: 3.4989x; 1.0725x over previous
//
#include <hip/hip_runtime.h>
#include <cstddef>
#include <cstdint>

#define N_NODES 50000
#define N_EDGES 800000
#define F_IN 50
#define K1PAD 64
#define H_DIM 512
#define O_DIM 121
#define O_PAD 128
#define N_GROUPS 20
#define EPSV 1e-5f
#define M_PAD 50048   // 391 * 128
#define M_TILES 391

#define STAT_SPLITS 32
#define SCAN_BLK 256
#define SCAN_NBLK ((N_NODES + SCAN_BLK - 1) / SCAN_BLK)  // 196

typedef unsigned short u16;
typedef __attribute__((ext_vector_type(8))) short short8;          // 8 bf16 (4 VGPRs)
typedef __attribute__((ext_vector_type(8))) unsigned short u16x8;  // 16B vector load
typedef __attribute__((ext_vector_type(4))) float f32x4;

__device__ __forceinline__ float b2f(u16 u) {
  union { unsigned int i; float f; } v; v.i = ((unsigned int)u) << 16; return v.f;
}
__device__ __forceinline__ u16 f2b(float f) {
  union { float f; unsigned int i; } v; v.f = f;
  unsigned int x = v.i;
  return (u16)((x + 0x7fffu + ((x >> 16) & 1u)) >> 16);  // RNE
}

__device__ __forceinline__ void gl_lds16(const void* g, void* l) {
  __builtin_amdgcn_global_load_lds(
      (__attribute__((address_space(1))) void*)(g),
      (__attribute__((address_space(3))) void*)(l), 16, 0, 0);
}

// ---------------- graph preprocessing ----------------

__global__ void k_deg(const int* __restrict__ dst, int* __restrict__ deg) {
  int e = blockIdx.x * blockDim.x + threadIdx.x;
  if (e < N_EDGES) atomicAdd(&deg[dst[e]], 1);
}

__global__ void k_scan1(const int* __restrict__ deg, int* __restrict__ off,
                        int* __restrict__ bsum) {
  __shared__ int buf[SCAN_BLK];
  int gid = blockIdx.x * SCAN_BLK + threadIdx.x;
  buf[threadIdx.x] = (gid < N_NODES) ? deg[gid] : 0;
  __syncthreads();
  for (int d = 1; d < SCAN_BLK; d <<= 1) {
    int t = (threadIdx.x >= d) ? buf[threadIdx.x - d] : 0;
    __syncthreads();
    buf[threadIdx.x] += t;
    __syncthreads();
  }
  if (gid < N_NODES) off[gid + 1] = buf[threadIdx.x];
  if (threadIdx.x == SCAN_BLK - 1) bsum[blockIdx.x] = buf[threadIdx.x];
}

__global__ void k_scan2(int* __restrict__ bsum) {
  __shared__ int buf[256];
  int t = threadIdx.x;
  buf[t] = (t < SCAN_NBLK) ? bsum[t] : 0;
  __syncthreads();
  for (int d = 1; d < 256; d <<= 1) {
    int v = (t >= d) ? buf[t - d] : 0;
    __syncthreads();
    buf[t] += v;
    __syncthreads();
  }
  if (t < SCAN_NBLK) bsum[t] = buf[t];
}

__global__ void k_scan3(int* __restrict__ off, const int* __restrict__ bsum) {
  int gid = blockIdx.x * SCAN_BLK + threadIdx.x;
  if (gid < N_NODES) {
    int add = (blockIdx.x > 0) ? bsum[blockIdx.x - 1] : 0;
    off[gid + 1] += add;
  }
  if (gid == 0) off[0] = 0;
}

__global__ void k_prep(const int* __restrict__ deg, const int* __restrict__ csr_off,
                       float* __restrict__ inv_deg, int* __restrict__ cursor) {
  int n = blockIdx.x * blockDim.x + threadIdx.x;
  if (n < N_NODES) {
    inv_deg[n] = 1.0f / (float)max(deg[n], 1);
    cursor[n] = csr_off[n];
  }
}

__global__ void k_scatter(const int* __restrict__ src, const int* __restrict__ dst,
                          int* __restrict__ cursor, int* __restrict__ csr_src) {
  int e = blockIdx.x * blockDim.x + threadIdx.x;
  if (e < N_EDGES) {
    int p = atomicAdd(&cursor[dst[e]], 1);
    csr_src[p] = src[e];
  }
}

__global__ void k_gbounds(const int* __restrict__ batch, int* __restrict__ gstart,
                          float* __restrict__ inv_sz) {
  int g = threadIdx.x;
  if (g <= N_GROUPS) {
    int lo = 0, hi = N_NODES;
    while (lo < hi) {
      int mid = (lo + hi) >> 1;
      if (batch[mid] < g) lo = mid + 1; else hi = mid;
    }
    gstart[g] = lo;
  }
  __syncthreads();
  if (g < N_GROUPS) {
    int sz = gstart[g + 1] - gstart[g];
    inv_sz[g] = 1.0f / (float)max(sz, 1);
  }
}

// ---------------- conversions ----------------

__global__ void k_xpad(const float* __restrict__ x, u16* __restrict__ xb) {
  int i = blockIdx.x * blockDim.x + threadIdx.x;
  if (i >= M_PAD * K1PAD) return;
  int r = i >> 6, c = i & (K1PAD - 1);
  float v = (r < N_NODES && c < F_IN) ? x[r * F_IN + c] : 0.f;
  xb[i] = f2b(v);
}

__global__ void k_wconv(const float* __restrict__ W, u16* __restrict__ Wb,
                        int Jreal, int Kin, int Jp, int Kp) {
  int i = blockIdx.x * blockDim.x + threadIdx.x;
  if (i >= Jp * Kp) return;
  int j = i / Kp, k = i - j * Kp;
  float v = (j < Jreal && k < Kin) ? W[j * Kin + k] : 0.f;
  Wb[i] = f2b(v);
}

// ---------------- aggregation ----------------

__global__ void k_agg_small(const float* __restrict__ x, const int* __restrict__ off,
                            const int* __restrict__ srcs, const float* __restrict__ inv_deg,
                            u16* __restrict__ agg) {
  int n = blockIdx.x;
  int f = threadIdx.x;  // 0..63
  int b = off[n], e = off[n + 1];
  float s = 0.f;
  if (f < F_IN)
    for (int i = b; i < e; ++i) s += x[(size_t)srcs[i] * F_IN + f];
  agg[(size_t)n * K1PAD + f] = f2b(s * inv_deg[n]);
}

// layers 2..5: 16B loads, one wave per node, 4 nodes/block, unroll-4 for MLP
__global__ __launch_bounds__(256) void k_agg512(
    const u16* __restrict__ h, const int* __restrict__ off,
    const int* __restrict__ srcs, const float* __restrict__ inv_deg,
    u16* __restrict__ agg) {
  int n = blockIdx.x * 4 + threadIdx.y;
  if (n >= N_NODES) return;
  int t = threadIdx.x;  // 0..63, 8 bf16 (16B) per lane covers a 512-col row
  int b = off[n], e = off[n + 1];
  float a[8] = {0.f, 0.f, 0.f, 0.f, 0.f, 0.f, 0.f, 0.f};
  int i = b;
  for (; i + 4 <= e; i += 4) {
    int s0 = srcs[i], s1 = srcs[i + 1], s2 = srcs[i + 2], s3 = srcs[i + 3];
    u16x8 v0 = ((const u16x8*)(h + (size_t)s0 * H_DIM))[t];
    u16x8 v1 = ((const u16x8*)(h + (size_t)s1 * H_DIM))[t];
    u16x8 v2 = ((const u16x8*)(h + (size_t)s2 * H_DIM))[t];
    u16x8 v3 = ((const u16x8*)(h + (size_t)s3 * H_DIM))[t];
#pragma unroll
    for (int j = 0; j < 8; ++j)
      a[j] += (b2f(v0[j]) + b2f(v1[j])) + (b2f(v2[j]) + b2f(v3[j]));
  }
  for (; i < e; ++i) {
    u16x8 v0 = ((const u16x8*)(h + (size_t)srcs[i] * H_DIM))[t];
#pragma unroll
    for (int j = 0; j < 8; ++j) a[j] += b2f(v0[j]);
  }
  float w = inv_deg[n];
  u16x8 r;
#pragma unroll
  for (int j = 0; j < 8; ++j) r[j] = f2b(a[j] * w);
  ((u16x8*)(agg + (size_t)n * H_DIM))[t] = r;
}

// ---------------- MFMA fused dual GEMM: C = A*Wl^T + X*Wr^T + b -------------
// JT = j-subtiles per wave (TN = 32*JT). 1D grid with XCD-aware swizzle:
// the JT j-blocks of one m-tile get ids with id%8 == m%8 (same XCD) and are
// temporally adjacent there -> A/X K-slabs reused from that XCD's L2.

#define TM 128
#define TK 32

template <int JT, bool BF16OUT>
__global__ __launch_bounds__(256) void k_gemm_mfma(
    const u16* __restrict__ A, const u16* __restrict__ X,
    const u16* __restrict__ Wl, const u16* __restrict__ Wr,
    const float* __restrict__ bias, void* __restrict__ Cout,
    int K, int Mreal, int Jreal) {
  constexpr int TN = JT * 32;
  __shared__ u16 As[TM * TK];
  __shared__ u16 Xs[TM * TK];
  __shared__ u16 Ls[TN * TK];
  __shared__ u16 Rs[TN * TK];

  // swizzled block-id decode
  int id = blockIdx.x;
  const int nfull = (M_TILES >> 3) * 8 * JT;  // full chunks of 8 m-tiles
  int m_t, j_t;
  if (id < nfull) {
    m_t = (id / (8 * JT)) * 8 + (id & 7);
    j_t = (id >> 3) & (JT - 1);
  } else {
    int rem = id - nfull;
    const int nrem = M_TILES & 7;  // 7
    m_t = (M_TILES & ~7) + rem % nrem;
    j_t = rem / nrem;
  }
  int m0 = m_t * TM;
  int j0 = j_t * TN;

  int tid = threadIdx.x;
  int lane = tid & 63;
  int wave = tid >> 6;
  int quad = lane >> 4;
  int lr = lane & 15;
  int wm = (wave & 1) * 64;
  int wn = (wave >> 1) * (JT * 16);

  f32x4 acc[4][JT] = {};

  // staging: thread t loads 16B; row = t/4, colgroup = t%4 -> row-major [64][32]
  int sr = tid >> 2;
  int sc = (tid & 3) * 8;
  size_t moff0 = (size_t)(m0 + sr) * K + sc;
  size_t moff1 = moff0 + (size_t)64 * K;
  size_t joff0 = (size_t)(j0 + sr) * K + sc;
  size_t joff1 = joff0 + (size_t)64 * K;
  const int dofs = tid * 8;

  for (int k0 = 0; k0 < K; k0 += TK) {
    __syncthreads();
    gl_lds16(A + moff0 + k0, As + dofs);
    gl_lds16(A + moff1 + k0, As + 2048 + dofs);
    gl_lds16(X + moff0 + k0, Xs + dofs);
    gl_lds16(X + moff1 + k0, Xs + 2048 + dofs);
    gl_lds16(Wl + joff0 + k0, Ls + dofs);
    if constexpr (JT == 4) gl_lds16(Wl + joff1 + k0, Ls + 2048 + dofs);
    gl_lds16(Wr + joff0 + k0, Rs + dofs);
    if constexpr (JT == 4) gl_lds16(Wr + joff1 + k0, Rs + 2048 + dofs);
    __syncthreads();
    short8 af[4], xf[4], lf[JT], rf[JT];
#pragma unroll
    for (int t = 0; t < 4; ++t) {
      int row = (wm + t * 16 + lr) * TK + quad * 8;
      af[t] = *(const short8*)(As + row);
      xf[t] = *(const short8*)(Xs + row);
    }
#pragma unroll
    for (int t = 0; t < JT; ++t) {
      int row = (wn + t * 16 + lr) * TK + quad * 8;
      lf[t] = *(const short8*)(Ls + row);
      rf[t] = *(const short8*)(Rs + row);
    }
#pragma unroll
    for (int ti = 0; ti < 4; ++ti)
#pragma unroll
      for (int tj = 0; tj < JT; ++tj) {
        acc[ti][tj] = __builtin_amdgcn_mfma_f32_16x16x32_bf16(
            af[ti], lf[tj], acc[ti][tj], 0, 0, 0);
        acc[ti][tj] = __builtin_amdgcn_mfma_f32_16x16x32_bf16(
            xf[ti], rf[tj], acc[ti][tj], 0, 0, 0);
      }
  }

  // epilogue: C/D layout col=lane&15, row=quad*4+reg (m89-verified)
#pragma unroll
  for (int tj = 0; tj < JT; ++tj) {
    int gcol = j0 + wn + tj * 16 + lr;
    float bv = (gcol < Jreal) ? bias[gcol] : 0.f;
#pragma unroll
    for (int ti = 0; ti < 4; ++ti) {
      f32x4 v = acc[ti][tj];
#pragma unroll
      for (int r = 0; r < 4; ++r) {
        int grow = m0 + wm + ti * 16 + quad * 4 + r;
        if (grow < Mreal && gcol < Jreal) {
          float val = v[r] + bv;
          if constexpr (BF16OUT)
            ((u16*)Cout)[(size_t)grow * Jreal + gcol] = f2b(val);
          else
            ((float*)Cout)[(size_t)grow * Jreal + gcol] = val;
        }
      }
    }
  }
}

// ---------------- GraphNorm ----------------

__global__ __launch_bounds__(512) void k_stats(
    const u16* __restrict__ h, const int* __restrict__ gstart,
    float* __restrict__ ssum, float* __restrict__ ssq) {
  int g = blockIdx.x;
  int sp = blockIdx.y;
  int f = threadIdx.x;
  int b = gstart[g], e = gstart[g + 1];
  int len = e - b;
  int chunk = (len + STAT_SPLITS - 1) / STAT_SPLITS;
  int lo = b + sp * chunk;
  int hi = min(lo + chunk, e);
  if (lo >= hi) return;
  float s = 0.f, q = 0.f;
  for (int n = lo; n < hi; ++n) {
    float v = b2f(h[(size_t)n * H_DIM + f]);
    s += v; q += v * v;
  }
  atomicAdd(&ssum[g * H_DIM + f], s);
  atomicAdd(&ssq[g * H_DIM + f], q);
}

// 8 cols per thread, 16B h load/store
__global__ void k_apply(u16* __restrict__ h, const int* __restrict__ batch,
                        const float* __restrict__ ssum, const float* __restrict__ ssq,
                        const float* __restrict__ inv_sz, const float* __restrict__ gw,
                        const float* __restrict__ gb, const float* __restrict__ alpha) {
  int tid = blockIdx.x * blockDim.x + threadIdx.x;
  if (tid >= N_NODES * (H_DIM / 8)) return;
  int n = tid >> 6;
  int c0 = (tid & 63) << 3;
  int g = batch[n];
  float is = inv_sz[g];
  u16x8 hv = *(const u16x8*)(h + (size_t)n * H_DIM + c0);
  u16x8 out;
#pragma unroll
  for (int j = 0; j < 8; ++j) {
    int f = c0 + j;
    float m = ssum[g * H_DIM + f] * is;
    float a = alpha[f];
    float ex2 = ssq[g * H_DIM + f] * is;
    float var = fmaxf(ex2 - a * (2.f - a) * m * m, 0.f);
    float o = b2f(hv[j]) - a * m;
    float y = o * rsqrtf(var + EPSV) * gw[f] + gb[f];
    out[j] = f2b(fmaxf(y, 0.f));
  }
  *(u16x8*)(h + (size_t)n * H_DIM + c0) = out;
}

// ---------------- driver ----------------

extern "C" void kernel_launch(void* const* d_in, const int* in_sizes, int n_in,
                              void* d_out, int out_size, void* d_ws, size_t ws_size,
                              hipStream_t stream) {
  const float* x = (const float*)d_in[0];
  const int* edge = (const int*)d_in[1];
  const int* batch = (const int*)d_in[2];
  const float *Wl[5], *Wr[5], *bb[5];
  for (int i = 0; i < 5; ++i) {
    Wl[i] = (const float*)d_in[3 + 3 * i];
    Wr[i] = (const float*)d_in[4 + 3 * i];
    bb[i] = (const float*)d_in[5 + 3 * i];
  }
  const float *gamma[4], *beta[4], *alpha[4];
  for (int i = 0; i < 4; ++i) {
    gamma[i] = (const float*)d_in[18 + 3 * i];
    beta[i]  = (const float*)d_in[19 + 3 * i];
    alpha[i] = (const float*)d_in[20 + 3 * i];
  }
  const int* srcv = edge;
  const int* dstv = edge + N_EDGES;

  char* base = (char*)d_ws;
  size_t off = 0;
  auto carve = [&](size_t bytes) -> char* {
    char* p = base + off;
    off = (off + bytes + 255) & ~(size_t)255;
    return p;
  };
  int* deg       = (int*)carve((size_t)N_NODES * 4);
  float* inv_deg = (float*)carve((size_t)N_NODES * 4);
  int* csr_off   = (int*)carve((size_t)(N_NODES + 1) * 4);
  int* cursor    = (int*)carve((size_t)N_NODES * 4);
  int* csr_src   = (int*)carve((size_t)N_EDGES * 4);
  int* bsum      = (int*)carve((size_t)SCAN_NBLK * 4);
  int* gstart    = (int*)carve((size_t)(N_GROUPS + 1) * 4);
  float* inv_sz  = (float*)carve((size_t)N_GROUPS * 4);
  float* ssum    = (float*)carve((size_t)N_GROUPS * H_DIM * 4);  // contiguous with ssq
  float* ssq     = (float*)carve((size_t)N_GROUPS * H_DIM * 4);
  u16* xb        = (u16*)carve((size_t)M_PAD * K1PAD * 2);
  u16* aggx      = (u16*)carve((size_t)M_PAD * K1PAD * 2);
  u16* h0        = (u16*)carve((size_t)M_PAD * H_DIM * 2);
  u16* h1        = (u16*)carve((size_t)M_PAD * H_DIM * 2);
  u16* h2        = (u16*)carve((size_t)M_PAD * H_DIM * 2);
  u16* w1lb = (u16*)carve((size_t)H_DIM * K1PAD * 2);
  u16* w1rb = (u16*)carve((size_t)H_DIM * K1PAD * 2);
  u16* w2lb = (u16*)carve((size_t)H_DIM * H_DIM * 2);
  u16* w2rb = (u16*)carve((size_t)H_DIM * H_DIM * 2);
  u16* w3lb = (u16*)carve((size_t)H_DIM * H_DIM * 2);
  u16* w3rb = (u16*)carve((size_t)H_DIM * H_DIM * 2);
  u16* w4lb = (u16*)carve((size_t)H_DIM * H_DIM * 2);
  u16* w4rb = (u16*)carve((size_t)H_DIM * H_DIM * 2);
  u16* w5lb = (u16*)carve((size_t)O_PAD * H_DIM * 2);
  u16* w5rb = (u16*)carve((size_t)O_PAD * H_DIM * 2);
  (void)ws_size; (void)in_sizes; (void)n_in; (void)out_size;

  // graph preprocessing
  hipMemsetAsync(deg, 0, (size_t)N_NODES * 4, stream);
  k_deg<<<(N_EDGES + 255) / 256, 256, 0, stream>>>(dstv, deg);
  k_scan1<<<SCAN_NBLK, SCAN_BLK, 0, stream>>>(deg, csr_off, bsum);
  k_scan2<<<1, 256, 0, stream>>>(bsum);
  k_scan3<<<SCAN_NBLK, SCAN_BLK, 0, stream>>>(csr_off, bsum);
  k_prep<<<(N_NODES + 255) / 256, 256, 0, stream>>>(deg, csr_off, inv_deg, cursor);
  k_scatter<<<(N_EDGES + 255) / 256, 256, 0, stream>>>(srcv, dstv, cursor, csr_src);
  k_gbounds<<<1, 64, 0, stream>>>(batch, gstart, inv_sz);
  k_xpad<<<(M_PAD * K1PAD + 255) / 256, 256, 0, stream>>>(x, xb);

  auto wconv = [&](const float* W, u16* Wb, int Jr, int Kin, int Jp, int Kp) {
    k_wconv<<<(Jp * Kp + 255) / 256, 256, 0, stream>>>(W, Wb, Jr, Kin, Jp, Kp);
  };
  wconv(Wl[0], w1lb, H_DIM, F_IN, H_DIM, K1PAD);
  wconv(Wr[0], w1rb, H_DIM, F_IN, H_DIM, K1PAD);
  wconv(Wl[1], w2lb, H_DIM, H_DIM, H_DIM, H_DIM);
  wconv(Wr[1], w2rb, H_DIM, H_DIM, H_DIM, H_DIM);
  wconv(Wl[2], w3lb, H_DIM, H_DIM, H_DIM, H_DIM);
  wconv(Wr[2], w3rb, H_DIM, H_DIM, H_DIM, H_DIM);
  wconv(Wl[3], w4lb, H_DIM, H_DIM, H_DIM, H_DIM);
  wconv(Wr[3], w4rb, H_DIM, H_DIM, H_DIM, H_DIM);
  wconv(Wl[4], w5lb, O_DIM, H_DIM, O_PAD, H_DIM);
  wconv(Wr[4], w5rb, O_DIM, H_DIM, O_PAD, H_DIM);

  const int nblk_main = M_TILES * 4;  // JT=4, TN=128 -> 1564
  const int nblk_l5   = M_TILES * 2;  // JT=2, TN=64  -> 782
  dim3 aggblk(64, 4);
  int aggrid = (N_NODES + 3) / 4;

  auto norm = [&](u16* h, int l) {
    hipMemsetAsync(ssum, 0, (size_t)N_GROUPS * H_DIM * 4 * 2, stream);  // ssum+ssq
    k_stats<<<dim3(N_GROUPS, STAT_SPLITS), 512, 0, stream>>>(h, gstart, ssum, ssq);
    k_apply<<<(N_NODES * (H_DIM / 8) + 255) / 256, 256, 0, stream>>>(
        h, batch, ssum, ssq, inv_sz, gamma[l], beta[l], alpha[l]);
  };

  // layer 1 (K = 64 padded)
  k_agg_small<<<N_NODES, 64, 0, stream>>>(x, csr_off, csr_src, inv_deg, aggx);
  k_gemm_mfma<4, true><<<nblk_main, 256, 0, stream>>>(aggx, xb, w1lb, w1rb, bb[0], h0,
                                                      K1PAD, M_PAD, H_DIM);
  norm(h0, 0);

  // layer 2
  k_agg512<<<aggrid, aggblk, 0, stream>>>(h0, csr_off, csr_src, inv_deg, h1);
  k_gemm_mfma<4, true><<<nblk_main, 256, 0, stream>>>(h1, h0, w2lb, w2rb, bb[1], h2,
                                                      H_DIM, M_PAD, H_DIM);
  norm(h2, 1);

  // layer 3
  k_agg512<<<aggrid, aggblk, 0, stream>>>(h2, csr_off, csr_src, inv_deg, h0);
  k_gemm_mfma<4, true><<<nblk_main, 256, 0, stream>>>(h0, h2, w3lb, w3rb, bb[2], h1,
                                                      H_DIM, M_PAD, H_DIM);
  norm(h1, 2);

  // layer 4
  k_agg512<<<aggrid, aggblk, 0, stream>>>(h1, csr_off, csr_src, inv_deg, h2);
  k_gemm_mfma<4, true><<<nblk_main, 256, 0, stream>>>(h2, h1, w4lb, w4rb, bb[3], h0,
                                                      H_DIM, M_PAD, H_DIM);
  norm(h0, 3);

  // layer 5 (J = 121, padded to 128; JT=2 -> TN=64, 782 blocks) -> d_out fp32
  k_agg512<<<aggrid, aggblk, 0, stream>>>(h0, csr_off, csr_src, inv_deg, h1);
  k_gemm_mfma<2, false><<<nblk_l5, 256, 0, stream>>>(h1, h0, w5lb, w5rb, bb[4],
                                                     (float*)d_out, H_DIM, N_NODES, O_DIM);
}

// Round 6
// 1199.787 us; speedup vs baseline: 3.9753x; 1.1362x over previous
//
#include <hip/hip_runtime.h>
#include <cstddef>
#include <cstdint>

#define N_NODES 50000
#define N_EDGES 800000
#define F_IN 50
#define K1PAD 64
#define H_DIM 512
#define O_DIM 121
#define N_GROUPS 20
#define EPSV 1e-5f
#define M_PAD 50048   // 391 * 128
#define M_TILES 391

#define STAT_SPLITS 32
#define SCAN_BLK 256
#define SCAN_NBLK ((N_NODES + SCAN_BLK - 1) / SCAN_BLK)  // 196
#define WALL_EL 1769472  // total padded bf16 weight elements

typedef unsigned short u16;
typedef __attribute__((ext_vector_type(8))) short short8;          // 8 bf16 (4 VGPRs)
typedef __attribute__((ext_vector_type(8))) unsigned short u16x8;  // 16B vector load
typedef __attribute__((ext_vector_type(4))) float f32x4;

__device__ __forceinline__ float b2f(u16 u) {
  union { unsigned int i; float f; } v; v.i = ((unsigned int)u) << 16; return v.f;
}
__device__ __forceinline__ u16 f2b(float f) {
  union { float f; unsigned int i; } v; v.f = f;
  unsigned int x = v.i;
  return (u16)((x + 0x7fffu + ((x >> 16) & 1u)) >> 16);  // RNE
}

__device__ __forceinline__ void gl_lds16(const void* g, void* l) {
  __builtin_amdgcn_global_load_lds(
      (__attribute__((address_space(1))) void*)(g),
      (__attribute__((address_space(3))) void*)(l), 16, 0, 0);
}

// ---------------- graph preprocessing ----------------

__global__ void k_deg(const int* __restrict__ dst, int* __restrict__ deg) {
  int e = blockIdx.x * blockDim.x + threadIdx.x;
  if (e < N_EDGES) atomicAdd(&deg[dst[e]], 1);
}

__global__ void k_scan1(const int* __restrict__ deg, int* __restrict__ off,
                        int* __restrict__ bsum) {
  __shared__ int buf[SCAN_BLK];
  int gid = blockIdx.x * SCAN_BLK + threadIdx.x;
  buf[threadIdx.x] = (gid < N_NODES) ? deg[gid] : 0;
  __syncthreads();
  for (int d = 1; d < SCAN_BLK; d <<= 1) {
    int t = (threadIdx.x >= d) ? buf[threadIdx.x - d] : 0;
    __syncthreads();
    buf[threadIdx.x] += t;
    __syncthreads();
  }
  if (gid < N_NODES) off[gid + 1] = buf[threadIdx.x];
  if (threadIdx.x == SCAN_BLK - 1) bsum[blockIdx.x] = buf[threadIdx.x];
}

__global__ void k_scan2(int* __restrict__ bsum) {
  __shared__ int buf[256];
  int t = threadIdx.x;
  buf[t] = (t < SCAN_NBLK) ? bsum[t] : 0;
  __syncthreads();
  for (int d = 1; d < 256; d <<= 1) {
    int v = (t >= d) ? buf[t - d] : 0;
    __syncthreads();
    buf[t] += v;
    __syncthreads();
  }
  if (t < SCAN_NBLK) bsum[t] = buf[t];
}

// scan finalize + inv_deg + cursor init, fused
__global__ void k_scan3prep(int* __restrict__ off, const int* __restrict__ bsum,
                            const int* __restrict__ deg, float* __restrict__ inv_deg,
                            int* __restrict__ cursor) {
  int gid = blockIdx.x * SCAN_BLK + threadIdx.x;
  if (gid < N_NODES) {
    int add = (blockIdx.x > 0) ? bsum[blockIdx.x - 1] : 0;
    int v = off[gid + 1] + add;
    off[gid + 1] = v;
    if (gid + 1 < N_NODES) cursor[gid + 1] = v;
    inv_deg[gid] = 1.0f / (float)max(deg[gid], 1);
  }
  if (gid == 0) { off[0] = 0; cursor[0] = 0; }
}

__global__ void k_scatter(const int* __restrict__ src, const int* __restrict__ dst,
                          int* __restrict__ cursor, int* __restrict__ csr_src) {
  int e = blockIdx.x * blockDim.x + threadIdx.x;
  if (e < N_EDGES) {
    int p = atomicAdd(&cursor[dst[e]], 1);
    csr_src[p] = src[e];
  }
}

__global__ void k_gbounds(const int* __restrict__ batch, int* __restrict__ gstart,
                          float* __restrict__ inv_sz) {
  int g = threadIdx.x;
  if (g <= N_GROUPS) {
    int lo = 0, hi = N_NODES;
    while (lo < hi) {
      int mid = (lo + hi) >> 1;
      if (batch[mid] < g) lo = mid + 1; else hi = mid;
    }
    gstart[g] = lo;
  }
  __syncthreads();
  if (g < N_GROUPS) {
    int sz = gstart[g + 1] - gstart[g];
    inv_sz[g] = 1.0f / (float)max(sz, 1);
  }
}

// ---------------- conversions ----------------

__global__ void k_xpad(const float* __restrict__ x, u16* __restrict__ xb) {
  int i = blockIdx.x * blockDim.x + threadIdx.x;
  if (i >= M_PAD * K1PAD) return;
  int r = i >> 6, c = i & (K1PAD - 1);
  float v = (r < N_NODES && c < F_IN) ? x[r * F_IN + c] : 0.f;
  xb[i] = f2b(v);
}

// all 10 weight conversions in one launch; wall layout (bf16 elements):
//  [0]      w1l 512x64   [32768]  w1r 512x64
//  [65536]  w2l 512x512  [327680] w2r  ... 6 blocks of 512x512 ...
//  [1638400] w5cat: rows 0-127 = W5l (121 real), rows 128-255 = W5r
struct WcSrc { const float* p[10]; };
__global__ void k_wconv_all(WcSrc s, u16* __restrict__ wall) {
  int idx = blockIdx.x * blockDim.x + threadIdx.x;
  if (idx >= WALL_EL) return;
  const int seg_start[10] = {0, 32768, 65536, 327680, 589824, 851968,
                             1114112, 1376256, 1638400, 1703936};
  const int jr[10]  = {512, 512, 512, 512, 512, 512, 512, 512, 121, 121};
  const int kin[10] = {50, 50, 512, 512, 512, 512, 512, 512, 512, 512};
  const int ksh[10] = {6, 6, 9, 9, 9, 9, 9, 9, 9, 9};
  int sgi = 0;
#pragma unroll
  for (int t = 1; t < 10; ++t)
    if (idx >= seg_start[t]) sgi = t;
  int local = idx - seg_start[sgi];
  int j = local >> ksh[sgi];
  int k = local & ((1 << ksh[sgi]) - 1);
  float v = (j < jr[sgi] && k < kin[sgi]) ? s.p[sgi][j * kin[sgi] + k] : 0.f;
  wall[idx] = f2b(v);
}

// ---------------- aggregation ----------------

// layer 1: gather bf16 xb rows (64 cols incl. zero pad)
__global__ void k_agg_small(const u16* __restrict__ xb, const int* __restrict__ off,
                            const int* __restrict__ srcs, const float* __restrict__ inv_deg,
                            u16* __restrict__ agg) {
  int n = blockIdx.x;
  int f = threadIdx.x;  // 0..63
  int b = off[n], e = off[n + 1];
  float s = 0.f;
  for (int i = b; i < e; ++i) s += b2f(xb[(size_t)srcs[i] * K1PAD + f]);
  agg[(size_t)n * K1PAD + f] = f2b(s * inv_deg[n]);
}

// layers 2..4: 16B loads, one wave per node, 4 nodes/block, unroll-8
__global__ __launch_bounds__(256) void k_agg512(
    const u16* __restrict__ h, const int* __restrict__ off,
    const int* __restrict__ srcs, const float* __restrict__ inv_deg,
    u16* __restrict__ agg) {
  int n = blockIdx.x * 4 + threadIdx.y;
  if (n >= N_NODES) return;
  int t = threadIdx.x;  // 0..63, 8 bf16 (16B) per lane covers a 512-col row
  int b = off[n], e = off[n + 1];
  float a[8] = {0.f, 0.f, 0.f, 0.f, 0.f, 0.f, 0.f, 0.f};
  int i = b;
  for (; i + 8 <= e; i += 8) {
    u16x8 v0 = ((const u16x8*)(h + (size_t)srcs[i + 0] * H_DIM))[t];
    u16x8 v1 = ((const u16x8*)(h + (size_t)srcs[i + 1] * H_DIM))[t];
    u16x8 v2 = ((const u16x8*)(h + (size_t)srcs[i + 2] * H_DIM))[t];
    u16x8 v3 = ((const u16x8*)(h + (size_t)srcs[i + 3] * H_DIM))[t];
    u16x8 v4 = ((const u16x8*)(h + (size_t)srcs[i + 4] * H_DIM))[t];
    u16x8 v5 = ((const u16x8*)(h + (size_t)srcs[i + 5] * H_DIM))[t];
    u16x8 v6 = ((const u16x8*)(h + (size_t)srcs[i + 6] * H_DIM))[t];
    u16x8 v7 = ((const u16x8*)(h + (size_t)srcs[i + 7] * H_DIM))[t];
#pragma unroll
    for (int j = 0; j < 8; ++j)
      a[j] += ((b2f(v0[j]) + b2f(v1[j])) + (b2f(v2[j]) + b2f(v3[j]))) +
              ((b2f(v4[j]) + b2f(v5[j])) + (b2f(v6[j]) + b2f(v7[j])));
  }
  for (; i < e; ++i) {
    u16x8 v0 = ((const u16x8*)(h + (size_t)srcs[i] * H_DIM))[t];
#pragma unroll
    for (int j = 0; j < 8; ++j) a[j] += b2f(v0[j]);
  }
  float w = inv_deg[n];
  u16x8 r;
#pragma unroll
  for (int j = 0; j < 8; ++j) r[j] = f2b(a[j] * w);
  ((u16x8*)(agg + (size_t)n * H_DIM))[t] = r;
}

// layer 5 final: out[n] = inv_deg[n]*sum(Pl[src]) + Pr[n] + bias (121 cols)
__global__ __launch_bounds__(256) void k_agg_final(
    const u16* __restrict__ Plb, const float* __restrict__ Prf,
    const int* __restrict__ off, const int* __restrict__ srcs,
    const float* __restrict__ inv_deg, const float* __restrict__ bias,
    float* __restrict__ out) {
  int n = blockIdx.x * 8 + (threadIdx.x >> 5);
  if (n >= N_NODES) return;
  int l = threadIdx.x & 31;  // 4 cols per lane over 128
  int c0 = l * 4;
  int b = off[n], e = off[n + 1];
  float a0 = 0.f, a1 = 0.f, a2 = 0.f, a3 = 0.f;
  int i = b;
  for (; i + 2 <= e; i += 2) {
    ushort4 v0 = ((const ushort4*)(Plb + (size_t)srcs[i] * 128))[l];
    ushort4 v1 = ((const ushort4*)(Plb + (size_t)srcs[i + 1] * 128))[l];
    a0 += b2f(v0.x) + b2f(v1.x); a1 += b2f(v0.y) + b2f(v1.y);
    a2 += b2f(v0.z) + b2f(v1.z); a3 += b2f(v0.w) + b2f(v1.w);
  }
  if (i < e) {
    ushort4 v0 = ((const ushort4*)(Plb + (size_t)srcs[i] * 128))[l];
    a0 += b2f(v0.x); a1 += b2f(v0.y); a2 += b2f(v0.z); a3 += b2f(v0.w);
  }
  float w = inv_deg[n];
  float4 pr = ((const float4*)(Prf + (size_t)n * 128))[l];
  float r0 = a0 * w + pr.x, r1 = a1 * w + pr.y;
  float r2 = a2 * w + pr.z, r3 = a3 * w + pr.w;
  size_t ob = (size_t)n * O_DIM;
  if (c0 + 0 < O_DIM) out[ob + c0 + 0] = r0 + bias[c0 + 0];
  if (c0 + 1 < O_DIM) out[ob + c0 + 1] = r1 + bias[c0 + 1];
  if (c0 + 2 < O_DIM) out[ob + c0 + 2] = r2 + bias[c0 + 2];
  if (c0 + 3 < O_DIM) out[ob + c0 + 3] = r3 + bias[c0 + 3];
}

// ---------------- MFMA GEMM ----------------
// DUAL:  C = A*Wl^T + X*Wr^T (+bias), bf16 out stride Jreal   (layers 1-4)
// !DUAL: P = A*Wl^T, OUTMODE1 split: cols<128 -> bf16 C0, cols>=128 -> f32 C1
// JB = number of j-blocks. XCD-aware swizzle: the JB j-blocks of one m-tile
// get ids with id%8 == m%8 (same XCD) and are temporally adjacent there.

#define TM 128
#define TK 32

template <int JB, bool DUAL, int OUTMODE>
__global__ __launch_bounds__(256) void k_gemm_mfma(
    const u16* __restrict__ A, const u16* __restrict__ X,
    const u16* __restrict__ Wl, const u16* __restrict__ Wr,
    const float* __restrict__ bias, void* __restrict__ C0,
    void* __restrict__ C1, int K, int Jreal) {
  __shared__ u16 As[TM * TK];
  __shared__ u16 Ls[TM * TK];
  __shared__ u16 Xs[DUAL ? TM * TK : 1];
  __shared__ u16 Rs[DUAL ? TM * TK : 1];

  int id = blockIdx.x;
  const int nfull = (M_TILES >> 3) * 8 * JB;
  int m_t, j_t;
  if (id < nfull) {
    m_t = (id / (8 * JB)) * 8 + (id & 7);
    j_t = (id >> 3) & (JB - 1);
  } else {
    int rem = id - nfull;
    const int nrem = M_TILES & 7;  // 7
    m_t = (M_TILES & ~7) + rem % nrem;
    j_t = rem / nrem;
  }
  int m0 = m_t * TM;
  int j0 = j_t * 128;

  int tid = threadIdx.x;
  int lane = tid & 63;
  int wave = tid >> 6;
  int quad = lane >> 4;
  int lr = lane & 15;
  int wm = (wave & 1) * 64;
  int wn = (wave >> 1) * 64;

  f32x4 acc[4][4] = {};

  int sr = tid >> 2;
  int sc = (tid & 3) * 8;
  size_t moff0 = (size_t)(m0 + sr) * K + sc;
  size_t moff1 = moff0 + (size_t)64 * K;
  size_t joff0 = (size_t)(j0 + sr) * K + sc;
  size_t joff1 = joff0 + (size_t)64 * K;
  const int dofs = tid * 8;

  for (int k0 = 0; k0 < K; k0 += TK) {
    __syncthreads();
    gl_lds16(A + moff0 + k0, As + dofs);
    gl_lds16(A + moff1 + k0, As + 2048 + dofs);
    gl_lds16(Wl + joff0 + k0, Ls + dofs);
    gl_lds16(Wl + joff1 + k0, Ls + 2048 + dofs);
    if constexpr (DUAL) {
      gl_lds16(X + moff0 + k0, Xs + dofs);
      gl_lds16(X + moff1 + k0, Xs + 2048 + dofs);
      gl_lds16(Wr + joff0 + k0, Rs + dofs);
      gl_lds16(Wr + joff1 + k0, Rs + 2048 + dofs);
    }
    __syncthreads();
    short8 af[4], lf[4];
#pragma unroll
    for (int t = 0; t < 4; ++t) {
      af[t] = *(const short8*)(As + (wm + t * 16 + lr) * TK + quad * 8);
      lf[t] = *(const short8*)(Ls + (wn + t * 16 + lr) * TK + quad * 8);
    }
#pragma unroll
    for (int ti = 0; ti < 4; ++ti)
#pragma unroll
      for (int tj = 0; tj < 4; ++tj)
        acc[ti][tj] = __builtin_amdgcn_mfma_f32_16x16x32_bf16(
            af[ti], lf[tj], acc[ti][tj], 0, 0, 0);
    if constexpr (DUAL) {
      short8 xf[4], rf[4];
#pragma unroll
      for (int t = 0; t < 4; ++t) {
        xf[t] = *(const short8*)(Xs + (wm + t * 16 + lr) * TK + quad * 8);
        rf[t] = *(const short8*)(Rs + (wn + t * 16 + lr) * TK + quad * 8);
      }
#pragma unroll
      for (int ti = 0; ti < 4; ++ti)
#pragma unroll
        for (int tj = 0; tj < 4; ++tj)
          acc[ti][tj] = __builtin_amdgcn_mfma_f32_16x16x32_bf16(
              xf[ti], rf[tj], acc[ti][tj], 0, 0, 0);
    }
  }

  // epilogue: C/D layout col=lane&15, row=quad*4+reg (m89-verified)
#pragma unroll
  for (int tj = 0; tj < 4; ++tj) {
    int gcol = j0 + wn + tj * 16 + lr;
    float bv = 0.f;
    if constexpr (OUTMODE == 0) bv = (gcol < Jreal) ? bias[gcol] : 0.f;
#pragma unroll
    for (int ti = 0; ti < 4; ++ti) {
      f32x4 v = acc[ti][tj];
#pragma unroll
      for (int r = 0; r < 4; ++r) {
        int grow = m0 + wm + ti * 16 + quad * 4 + r;
        if constexpr (OUTMODE == 0) {
          if (gcol < Jreal)
            ((u16*)C0)[(size_t)grow * Jreal + gcol] = f2b(v[r] + bv);
        } else {
          if (gcol < 128)
            ((u16*)C0)[(size_t)grow * 128 + gcol] = f2b(v[r]);
          else
            ((float*)C1)[(size_t)grow * 128 + (gcol - 128)] = v[r];
        }
      }
    }
  }
}

// ---------------- GraphNorm ----------------

__global__ __launch_bounds__(512) void k_stats(
    const u16* __restrict__ h, const int* __restrict__ gstart,
    float* __restrict__ ssum, float* __restrict__ ssq) {
  int g = blockIdx.x;
  int sp = blockIdx.y;
  int f = threadIdx.x;
  int b = gstart[g], e = gstart[g + 1];
  int len = e - b;
  int chunk = (len + STAT_SPLITS - 1) / STAT_SPLITS;
  int lo = b + sp * chunk;
  int hi = min(lo + chunk, e);
  if (lo >= hi) return;
  float s = 0.f, q = 0.f;
  for (int n = lo; n < hi; ++n) {
    float v = b2f(h[(size_t)n * H_DIM + f]);
    s += v; q += v * v;
  }
  atomicAdd(&ssum[g * H_DIM + f], s);
  atomicAdd(&ssq[g * H_DIM + f], q);
}

__global__ void k_apply(u16* __restrict__ h, const int* __restrict__ batch,
                        const float* __restrict__ ssum, const float* __restrict__ ssq,
                        const float* __restrict__ inv_sz, const float* __restrict__ gw,
                        const float* __restrict__ gb, const float* __restrict__ alpha) {
  int tid = blockIdx.x * blockDim.x + threadIdx.x;
  if (tid >= N_NODES * (H_DIM / 8)) return;
  int n = tid >> 6;
  int c0 = (tid & 63) << 3;
  int g = batch[n];
  float is = inv_sz[g];
  u16x8 hv = *(const u16x8*)(h + (size_t)n * H_DIM + c0);
  u16x8 out;
#pragma unroll
  for (int j = 0; j < 8; ++j) {
    int f = c0 + j;
    float m = ssum[g * H_DIM + f] * is;
    float a = alpha[f];
    float ex2 = ssq[g * H_DIM + f] * is;
    float var = fmaxf(ex2 - a * (2.f - a) * m * m, 0.f);
    float o = b2f(hv[j]) - a * m;
    float y = o * rsqrtf(var + EPSV) * gw[f] + gb[f];
    out[j] = f2b(fmaxf(y, 0.f));
  }
  *(u16x8*)(h + (size_t)n * H_DIM + c0) = out;
}

// ---------------- driver ----------------

extern "C" void kernel_launch(void* const* d_in, const int* in_sizes, int n_in,
                              void* d_out, int out_size, void* d_ws, size_t ws_size,
                              hipStream_t stream) {
  const float* x = (const float*)d_in[0];
  const int* edge = (const int*)d_in[1];
  const int* batch = (const int*)d_in[2];
  const float *Wl[5], *Wr[5], *bb[5];
  for (int i = 0; i < 5; ++i) {
    Wl[i] = (const float*)d_in[3 + 3 * i];
    Wr[i] = (const float*)d_in[4 + 3 * i];
    bb[i] = (const float*)d_in[5 + 3 * i];
  }
  const float *gamma[4], *beta[4], *alpha[4];
  for (int i = 0; i < 4; ++i) {
    gamma[i] = (const float*)d_in[18 + 3 * i];
    beta[i]  = (const float*)d_in[19 + 3 * i];
    alpha[i] = (const float*)d_in[20 + 3 * i];
  }
  const int* srcv = edge;
  const int* dstv = edge + N_EDGES;

  char* base = (char*)d_ws;
  size_t off = 0;
  auto carve = [&](size_t bytes) -> char* {
    char* p = base + off;
    off = (off + bytes + 255) & ~(size_t)255;
    return p;
  };
  int* deg       = (int*)carve((size_t)N_NODES * 4);
  float* inv_deg = (float*)carve((size_t)N_NODES * 4);
  int* csr_off   = (int*)carve((size_t)(N_NODES + 1) * 4);
  int* cursor    = (int*)carve((size_t)N_NODES * 4);
  int* csr_src   = (int*)carve((size_t)N_EDGES * 4);
  int* bsum      = (int*)carve((size_t)SCAN_NBLK * 4);
  int* gstart    = (int*)carve((size_t)(N_GROUPS + 1) * 4);
  float* inv_sz  = (float*)carve((size_t)N_GROUPS * 4);
  float* stats   = (float*)carve((size_t)4 * 2 * N_GROUPS * H_DIM * 4);  // per-layer ssum|ssq
  u16* xb        = (u16*)carve((size_t)M_PAD * K1PAD * 2);
  u16* aggx      = (u16*)carve((size_t)M_PAD * K1PAD * 2);
  u16* h0        = (u16*)carve((size_t)M_PAD * H_DIM * 2);
  u16* h1        = (u16*)carve((size_t)M_PAD * H_DIM * 2);
  u16* h2        = (u16*)carve((size_t)M_PAD * H_DIM * 2);
  u16* wall      = (u16*)carve((size_t)WALL_EL * 2);
  (void)ws_size; (void)in_sizes; (void)n_in; (void)out_size;

  // weight sub-pointers inside wall (layout matches k_wconv_all)
  u16* w1lb = wall;
  u16* w1rb = wall + 32768;
  u16* w2lb = wall + 65536;
  u16* w2rb = wall + 327680;
  u16* w3lb = wall + 589824;
  u16* w3rb = wall + 851968;
  u16* w4lb = wall + 1114112;
  u16* w4rb = wall + 1376256;
  u16* w5cat = wall + 1638400;  // 256 x 512

  // L5 P buffers alias h1 (free at L5): Plb bf16 [M_PAD x 128], Prf f32 [M_PAD x 128]
  u16* Plb = h1;
  float* Prf = (float*)((char*)h1 + (size_t)M_PAD * 128 * 2);

  // graph preprocessing
  hipMemsetAsync(deg, 0, (size_t)N_NODES * 4, stream);
  k_deg<<<(N_EDGES + 255) / 256, 256, 0, stream>>>(dstv, deg);
  k_scan1<<<SCAN_NBLK, SCAN_BLK, 0, stream>>>(deg, csr_off, bsum);
  k_scan2<<<1, 256, 0, stream>>>(bsum);
  k_scan3prep<<<SCAN_NBLK, SCAN_BLK, 0, stream>>>(csr_off, bsum, deg, inv_deg, cursor);
  k_scatter<<<(N_EDGES + 255) / 256, 256, 0, stream>>>(srcv, dstv, cursor, csr_src);
  k_gbounds<<<1, 64, 0, stream>>>(batch, gstart, inv_sz);
  k_xpad<<<(M_PAD * K1PAD + 255) / 256, 256, 0, stream>>>(x, xb);

  WcSrc ws_src;
  ws_src.p[0] = Wl[0]; ws_src.p[1] = Wr[0];
  ws_src.p[2] = Wl[1]; ws_src.p[3] = Wr[1];
  ws_src.p[4] = Wl[2]; ws_src.p[5] = Wr[2];
  ws_src.p[6] = Wl[3]; ws_src.p[7] = Wr[3];
  ws_src.p[8] = Wl[4]; ws_src.p[9] = Wr[4];
  k_wconv_all<<<(WALL_EL + 255) / 256, 256, 0, stream>>>(ws_src, wall);

  hipMemsetAsync(stats, 0, (size_t)4 * 2 * N_GROUPS * H_DIM * 4, stream);

  const int nblk_main = M_TILES * 4;  // JB=4
  const int nblk_l5   = M_TILES * 2;  // JB=2
  dim3 aggblk(64, 4);
  int aggrid = (N_NODES + 3) / 4;

  auto norm = [&](u16* h, int l) {
    float* ss = stats + (size_t)l * 2 * N_GROUPS * H_DIM;
    float* sq = ss + N_GROUPS * H_DIM;
    k_stats<<<dim3(N_GROUPS, STAT_SPLITS), 512, 0, stream>>>(h, gstart, ss, sq);
    k_apply<<<(N_NODES * (H_DIM / 8) + 255) / 256, 256, 0, stream>>>(
        h, batch, ss, sq, inv_sz, gamma[l], beta[l], alpha[l]);
  };

  // layer 1 (K = 64 padded)
  k_agg_small<<<N_NODES, 64, 0, stream>>>(xb, csr_off, csr_src, inv_deg, aggx);
  k_gemm_mfma<4, true, 0><<<nblk_main, 256, 0, stream>>>(
      aggx, xb, w1lb, w1rb, bb[0], h0, nullptr, K1PAD, H_DIM);
  norm(h0, 0);

  // layer 2
  k_agg512<<<aggrid, aggblk, 0, stream>>>(h0, csr_off, csr_src, inv_deg, h1);
  k_gemm_mfma<4, true, 0><<<nblk_main, 256, 0, stream>>>(
      h1, h0, w2lb, w2rb, bb[1], h2, nullptr, H_DIM, H_DIM);
  norm(h2, 1);

  // layer 3
  k_agg512<<<aggrid, aggblk, 0, stream>>>(h2, csr_off, csr_src, inv_deg, h0);
  k_gemm_mfma<4, true, 0><<<nblk_main, 256, 0, stream>>>(
      h0, h2, w3lb, w3rb, bb[2], h1, nullptr, H_DIM, H_DIM);
  norm(h1, 2);

  // layer 4
  k_agg512<<<aggrid, aggblk, 0, stream>>>(h1, csr_off, csr_src, inv_deg, h2);
  k_gemm_mfma<4, true, 0><<<nblk_main, 256, 0, stream>>>(
      h2, h1, w4lb, w4rb, bb[3], h0, nullptr, H_DIM, H_DIM);
  norm(h0, 3);

  // layer 5 via linearity: P = h0 @ [W5l|W5r]^T (J=256), then
  // out = inv_deg * segsum(Pl[src]) + Pr + b5
  k_gemm_mfma<2, false, 1><<<nblk_l5, 256, 0, stream>>>(
      h0, nullptr, w5cat, nullptr, nullptr, Plb, Prf, H_DIM, 256);
  k_agg_final<<<(N_NODES + 7) / 8, 256, 0, stream>>>(
      Plb, Prf, csr_off, csr_src, inv_deg, bb[4], (float*)d_out);
}

// Round 7
// 1088.432 us; speedup vs baseline: 4.3820x; 1.1023x over previous
//
#include <hip/hip_runtime.h>
#include <cstddef>
#include <cstdint>

#define N_NODES 50000
#define N_EDGES 800000
#define F_IN 50
#define K1PAD 64
#define H_DIM 512
#define O_DIM 121
#define N_GROUPS 20
#define EPSV 1e-5f
#define M_PAD 50048   // 391 * 128
#define M_TILES 391

#define SCAN_BLK 256
#define SCAN_NBLK ((N_NODES + SCAN_BLK - 1) / SCAN_BLK)  // 196
#define WALL_EL 1769472
#define XB_EL (M_PAD * K1PAD)

typedef unsigned short u16;
typedef __attribute__((ext_vector_type(8))) short short8;          // 8 bf16 (4 VGPRs)
typedef __attribute__((ext_vector_type(8))) unsigned short u16x8;  // 16B vector load
typedef __attribute__((ext_vector_type(4))) float f32x4;

__device__ __forceinline__ float b2f(u16 u) {
  union { unsigned int i; float f; } v; v.i = ((unsigned int)u) << 16; return v.f;
}
__device__ __forceinline__ u16 f2b(float f) {
  union { float f; unsigned int i; } v; v.f = f;
  unsigned int x = v.i;
  return (u16)((x + 0x7fffu + ((x >> 16) & 1u)) >> 16);  // RNE
}

__device__ __forceinline__ void gl_lds16(const void* g, void* l) {
  __builtin_amdgcn_global_load_lds(
      (__attribute__((address_space(1))) void*)(g),
      (__attribute__((address_space(3))) void*)(l), 16, 0, 0);
}

// ---------------- graph preprocessing ----------------

__global__ void k_deg(const int* __restrict__ dst, int* __restrict__ deg) {
  int e = blockIdx.x * blockDim.x + threadIdx.x;
  if (e < N_EDGES) atomicAdd(&deg[dst[e]], 1);
}

__global__ void k_scan1(const int* __restrict__ deg, int* __restrict__ off,
                        int* __restrict__ bsum) {
  __shared__ int buf[SCAN_BLK];
  int gid = blockIdx.x * SCAN_BLK + threadIdx.x;
  buf[threadIdx.x] = (gid < N_NODES) ? deg[gid] : 0;
  __syncthreads();
  for (int d = 1; d < SCAN_BLK; d <<= 1) {
    int t = (threadIdx.x >= d) ? buf[threadIdx.x - d] : 0;
    __syncthreads();
    buf[threadIdx.x] += t;
    __syncthreads();
  }
  if (gid < N_NODES) off[gid + 1] = buf[threadIdx.x];
  if (threadIdx.x == SCAN_BLK - 1) bsum[blockIdx.x] = buf[threadIdx.x];
}

// block 0: scan of block sums; block 1: group bounds from sorted batch
__global__ void k_scan2_gbounds(int* __restrict__ bsum, const int* __restrict__ batch,
                                int* __restrict__ gstart, float* __restrict__ inv_sz) {
  int t = threadIdx.x;
  if (blockIdx.x == 0) {
    __shared__ int buf[256];
    buf[t] = (t < SCAN_NBLK) ? bsum[t] : 0;
    __syncthreads();
    for (int d = 1; d < 256; d <<= 1) {
      int v = (t >= d) ? buf[t - d] : 0;
      __syncthreads();
      buf[t] += v;
      __syncthreads();
    }
    if (t < SCAN_NBLK) bsum[t] = buf[t];
  } else {
    if (t <= N_GROUPS) {
      int lo = 0, hi = N_NODES;
      while (lo < hi) {
        int mid = (lo + hi) >> 1;
        if (batch[mid] < t) lo = mid + 1; else hi = mid;
      }
      gstart[t] = lo;
    }
    __syncthreads();
    if (t < N_GROUPS) {
      int sz = gstart[t + 1] - gstart[t];
      inv_sz[t] = 1.0f / (float)max(sz, 1);
    }
  }
}

__global__ void k_scan3prep(int* __restrict__ off, const int* __restrict__ bsum,
                            const int* __restrict__ deg, float* __restrict__ inv_deg,
                            int* __restrict__ cursor) {
  int gid = blockIdx.x * SCAN_BLK + threadIdx.x;
  if (gid < N_NODES) {
    int add = (blockIdx.x > 0) ? bsum[blockIdx.x - 1] : 0;
    int v = off[gid + 1] + add;
    off[gid + 1] = v;
    if (gid + 1 < N_NODES) cursor[gid + 1] = v;
    inv_deg[gid] = 1.0f / (float)max(deg[gid], 1);
  }
  if (gid == 0) { off[0] = 0; cursor[0] = 0; }
}

__global__ void k_scatter(const int* __restrict__ src, const int* __restrict__ dst,
                          int* __restrict__ cursor, int* __restrict__ csr_src) {
  int e = blockIdx.x * blockDim.x + threadIdx.x;
  if (e < N_EDGES) {
    int p = atomicAdd(&cursor[dst[e]], 1);
    csr_src[p] = src[e];
  }
}

// ---------------- conversions (x pad + all weights, one launch) -------------
//  wall layout (bf16 elements):
//  [0] w1l 512x64  [32768] w1r 512x64  [65536..] w2l..w4r 6 x 512x512
//  [1638400] w5cat: rows 0-127 = W5l (121 real), rows 128-255 = W5r
struct WcSrc { const float* p[10]; };
__global__ void k_convert_all(const float* __restrict__ x, WcSrc s,
                              u16* __restrict__ xb, u16* __restrict__ wall) {
  int idx = blockIdx.x * blockDim.x + threadIdx.x;
  if (idx < XB_EL) {
    int r = idx >> 6, c = idx & (K1PAD - 1);
    float v = (r < N_NODES && c < F_IN) ? x[r * F_IN + c] : 0.f;
    xb[idx] = f2b(v);
    return;
  }
  idx -= XB_EL;
  if (idx >= WALL_EL) return;
  const int seg_start[10] = {0, 32768, 65536, 327680, 589824, 851968,
                             1114112, 1376256, 1638400, 1703936};
  const int jr[10]  = {512, 512, 512, 512, 512, 512, 512, 512, 121, 121};
  const int kin[10] = {50, 50, 512, 512, 512, 512, 512, 512, 512, 512};
  const int ksh[10] = {6, 6, 9, 9, 9, 9, 9, 9, 9, 9};
  int sgi = 0;
#pragma unroll
  for (int t = 1; t < 10; ++t)
    if (idx >= seg_start[t]) sgi = t;
  int local = idx - seg_start[sgi];
  int j = local >> ksh[sgi];
  int k = local & ((1 << ksh[sgi]) - 1);
  float v = (j < jr[sgi] && k < kin[sgi]) ? s.p[sgi][j * kin[sgi] + k] : 0.f;
  wall[idx] = f2b(v);
}

// ---------------- aggregation ----------------

__global__ void k_agg_small(const u16* __restrict__ xb, const int* __restrict__ off,
                            const int* __restrict__ srcs, const float* __restrict__ inv_deg,
                            u16* __restrict__ agg) {
  int n = blockIdx.x;
  int f = threadIdx.x;  // 0..63
  int b = off[n], e = off[n + 1];
  float s = 0.f;
  for (int i = b; i < e; ++i) s += b2f(xb[(size_t)srcs[i] * K1PAD + f]);
  agg[(size_t)n * K1PAD + f] = f2b(s * inv_deg[n]);
}

// layers 2..4: 16B loads, 2 waves per node (edge split), 4 nodes per block
__global__ __launch_bounds__(512) void k_agg512(
    const u16* __restrict__ h, const int* __restrict__ off,
    const int* __restrict__ srcs, const float* __restrict__ inv_deg,
    u16* __restrict__ agg) {
  __shared__ float part[4][64][8];  // 8 KB
  int slot = threadIdx.y >> 1;
  int sub = threadIdx.y & 1;
  int n = blockIdx.x * 4 + slot;
  int t = threadIdx.x;  // 0..63, 8 bf16 (16B) per lane covers a 512-col row
  float a[8] = {0.f, 0.f, 0.f, 0.f, 0.f, 0.f, 0.f, 0.f};
  if (n < N_NODES) {
    int b = off[n], e = off[n + 1];
    int half = (e - b + 1) >> 1;
    int lo = b + sub * half;
    int hi = min(lo + half, e);
    int i = lo;
    for (; i + 4 <= hi; i += 4) {
      u16x8 v0 = ((const u16x8*)(h + (size_t)srcs[i + 0] * H_DIM))[t];
      u16x8 v1 = ((const u16x8*)(h + (size_t)srcs[i + 1] * H_DIM))[t];
      u16x8 v2 = ((const u16x8*)(h + (size_t)srcs[i + 2] * H_DIM))[t];
      u16x8 v3 = ((const u16x8*)(h + (size_t)srcs[i + 3] * H_DIM))[t];
#pragma unroll
      for (int j = 0; j < 8; ++j)
        a[j] += (b2f(v0[j]) + b2f(v1[j])) + (b2f(v2[j]) + b2f(v3[j]));
    }
    for (; i < hi; ++i) {
      u16x8 v0 = ((const u16x8*)(h + (size_t)srcs[i] * H_DIM))[t];
#pragma unroll
      for (int j = 0; j < 8; ++j) a[j] += b2f(v0[j]);
    }
  }
  if (sub == 1) {
#pragma unroll
    for (int j = 0; j < 8; ++j) part[slot][t][j] = a[j];
  }
  __syncthreads();
  if (sub == 0 && n < N_NODES) {
    float w = inv_deg[n];
    u16x8 r;
#pragma unroll
    for (int j = 0; j < 8; ++j) r[j] = f2b((a[j] + part[slot][t][j]) * w);
    ((u16x8*)(agg + (size_t)n * H_DIM))[t] = r;
  }
}

// layer 5 final: out[n] = inv_deg[n]*sum(Pl[src]) + Pr[n] + bias (121 cols)
__global__ __launch_bounds__(256) void k_agg_final(
    const u16* __restrict__ Plb, const float* __restrict__ Prf,
    const int* __restrict__ off, const int* __restrict__ srcs,
    const float* __restrict__ inv_deg, const float* __restrict__ bias,
    float* __restrict__ out) {
  int n = blockIdx.x * 8 + (threadIdx.x >> 5);
  if (n >= N_NODES) return;
  int l = threadIdx.x & 31;
  int c0 = l * 4;
  int b = off[n], e = off[n + 1];
  float a0 = 0.f, a1 = 0.f, a2 = 0.f, a3 = 0.f;
  int i = b;
  for (; i + 2 <= e; i += 2) {
    ushort4 v0 = ((const ushort4*)(Plb + (size_t)srcs[i] * 128))[l];
    ushort4 v1 = ((const ushort4*)(Plb + (size_t)srcs[i + 1] * 128))[l];
    a0 += b2f(v0.x) + b2f(v1.x); a1 += b2f(v0.y) + b2f(v1.y);
    a2 += b2f(v0.z) + b2f(v1.z); a3 += b2f(v0.w) + b2f(v1.w);
  }
  if (i < e) {
    ushort4 v0 = ((const ushort4*)(Plb + (size_t)srcs[i] * 128))[l];
    a0 += b2f(v0.x); a1 += b2f(v0.y); a2 += b2f(v0.z); a3 += b2f(v0.w);
  }
  float w = inv_deg[n];
  float4 pr = ((const float4*)(Prf + (size_t)n * 128))[l];
  float r0 = a0 * w + pr.x, r1 = a1 * w + pr.y;
  float r2 = a2 * w + pr.z, r3 = a3 * w + pr.w;
  size_t ob = (size_t)n * O_DIM;
  if (c0 + 0 < O_DIM) out[ob + c0 + 0] = r0 + bias[c0 + 0];
  if (c0 + 1 < O_DIM) out[ob + c0 + 1] = r1 + bias[c0 + 1];
  if (c0 + 2 < O_DIM) out[ob + c0 + 2] = r2 + bias[c0 + 2];
  if (c0 + 3 < O_DIM) out[ob + c0 + 3] = r3 + bias[c0 + 3];
}

// ---------------- MFMA GEMM ----------------
// DUAL(OUTMODE 0): C = A*Wl^T + X*Wr^T + b, bf16 out [*, 512]; GraphNorm
//   stats (sum, sumsq incl. bias, pre-relu) fused into epilogue via
//   cross-quad shfl reduce + atomics. Guarded path for group-boundary /
//   M-pad tiles.
// !DUAL(OUTMODE 1): P = A*Wl^T; cols<128 -> bf16 C0, cols>=128 -> f32 C1.
// XCD-aware swizzle: the JB j-blocks of one m-tile get ids with
// id%8 == m%8 (same XCD) and are temporally adjacent there.

#define TM 128
#define TK 32

template <int JB, bool DUAL, int OUTMODE>
__global__ __launch_bounds__(256) void k_gemm_mfma(
    const u16* __restrict__ A, const u16* __restrict__ X,
    const u16* __restrict__ Wl, const u16* __restrict__ Wr,
    const float* __restrict__ bias, void* __restrict__ C0,
    void* __restrict__ C1, const int* __restrict__ batch,
    float* __restrict__ ssum, float* __restrict__ ssq, int K) {
  __shared__ u16 As[TM * TK];
  __shared__ u16 Ls[TM * TK];
  __shared__ u16 Xs[DUAL ? TM * TK : 1];
  __shared__ u16 Rs[DUAL ? TM * TK : 1];

  int id = blockIdx.x;
  const int nfull = (M_TILES >> 3) * 8 * JB;
  int m_t, j_t;
  if (id < nfull) {
    m_t = (id / (8 * JB)) * 8 + (id & 7);
    j_t = (id >> 3) & (JB - 1);
  } else {
    int rem = id - nfull;
    const int nrem = M_TILES & 7;  // 7
    m_t = (M_TILES & ~7) + rem % nrem;
    j_t = rem / nrem;
  }
  int m0 = m_t * TM;
  int j0 = j_t * 128;

  int tid = threadIdx.x;
  int lane = tid & 63;
  int wave = tid >> 6;
  int quad = lane >> 4;
  int lr = lane & 15;
  int wm = (wave & 1) * 64;
  int wn = (wave >> 1) * 64;

  f32x4 acc[4][4] = {};

  int sr = tid >> 2;
  int sc = (tid & 3) * 8;
  size_t moff0 = (size_t)(m0 + sr) * K + sc;
  size_t moff1 = moff0 + (size_t)64 * K;
  size_t joff0 = (size_t)(j0 + sr) * K + sc;
  size_t joff1 = joff0 + (size_t)64 * K;
  const int dofs = tid * 8;

  for (int k0 = 0; k0 < K; k0 += TK) {
    __syncthreads();
    gl_lds16(A + moff0 + k0, As + dofs);
    gl_lds16(A + moff1 + k0, As + 2048 + dofs);
    gl_lds16(Wl + joff0 + k0, Ls + dofs);
    gl_lds16(Wl + joff1 + k0, Ls + 2048 + dofs);
    if constexpr (DUAL) {
      gl_lds16(X + moff0 + k0, Xs + dofs);
      gl_lds16(X + moff1 + k0, Xs + 2048 + dofs);
      gl_lds16(Wr + joff0 + k0, Rs + dofs);
      gl_lds16(Wr + joff1 + k0, Rs + 2048 + dofs);
    }
    __syncthreads();
    short8 af[4], lf[4];
#pragma unroll
    for (int t = 0; t < 4; ++t) {
      af[t] = *(const short8*)(As + (wm + t * 16 + lr) * TK + quad * 8);
      lf[t] = *(const short8*)(Ls + (wn + t * 16 + lr) * TK + quad * 8);
    }
#pragma unroll
    for (int ti = 0; ti < 4; ++ti)
#pragma unroll
      for (int tj = 0; tj < 4; ++tj)
        acc[ti][tj] = __builtin_amdgcn_mfma_f32_16x16x32_bf16(
            af[ti], lf[tj], acc[ti][tj], 0, 0, 0);
    if constexpr (DUAL) {
      short8 xf[4], rf[4];
#pragma unroll
      for (int t = 0; t < 4; ++t) {
        xf[t] = *(const short8*)(Xs + (wm + t * 16 + lr) * TK + quad * 8);
        rf[t] = *(const short8*)(Rs + (wn + t * 16 + lr) * TK + quad * 8);
      }
#pragma unroll
      for (int ti = 0; ti < 4; ++ti)
#pragma unroll
        for (int tj = 0; tj < 4; ++tj)
          acc[ti][tj] = __builtin_amdgcn_mfma_f32_16x16x32_bf16(
              xf[ti], rf[tj], acc[ti][tj], 0, 0, 0);
    }
  }

  // epilogue: C/D layout col=lane&15, row=quad*4+reg (m89-verified)
  if constexpr (OUTMODE == 0) {
    int glo = batch[m0];
    int lastrow = m0 + TM - 1;
    bool fast = (lastrow < N_NODES) && (batch[lastrow] == glo);
#pragma unroll
    for (int tj = 0; tj < 4; ++tj) {
      int gcol = j0 + wn + tj * 16 + lr;  // < 512 always here
      float bv = bias[gcol];
      float s = 0.f, q = 0.f;
#pragma unroll
      for (int ti = 0; ti < 4; ++ti) {
        f32x4 v = acc[ti][tj];
        int rbase = m0 + wm + ti * 16 + quad * 4;
        if (fast) {
#pragma unroll
          for (int r = 0; r < 4; ++r) {
            float val = v[r] + bv;
            ((u16*)C0)[(size_t)(rbase + r) * H_DIM + gcol] = f2b(val);
            s += val; q += val * val;
          }
        } else {
          // guarded: 4-row run is contiguous in m; groups may split it
          if (rbase + 3 < N_NODES && batch[rbase] == batch[rbase + 3]) {
            float s4 = 0.f, q4 = 0.f;
#pragma unroll
            for (int r = 0; r < 4; ++r) {
              float val = v[r] + bv;
              ((u16*)C0)[(size_t)(rbase + r) * H_DIM + gcol] = f2b(val);
              s4 += val; q4 += val * val;
            }
            int g = batch[rbase];
            atomicAdd(&ssum[g * H_DIM + gcol], s4);
            atomicAdd(&ssq[g * H_DIM + gcol], q4);
          } else {
#pragma unroll
            for (int r = 0; r < 4; ++r) {
              int grow = rbase + r;
              if (grow < N_NODES) {
                float val = v[r] + bv;
                ((u16*)C0)[(size_t)grow * H_DIM + gcol] = f2b(val);
                int g = batch[grow];
                atomicAdd(&ssum[g * H_DIM + gcol], val);
                atomicAdd(&ssq[g * H_DIM + gcol], val * val);
              }
            }
          }
        }
      }
      if (fast) {
        s += __shfl_xor(s, 16); s += __shfl_xor(s, 32);
        q += __shfl_xor(q, 16); q += __shfl_xor(q, 32);
        if (quad == 0) {
          atomicAdd(&ssum[glo * H_DIM + gcol], s);
          atomicAdd(&ssq[glo * H_DIM + gcol], q);
        }
      }
    }
  } else {
#pragma unroll
    for (int tj = 0; tj < 4; ++tj) {
      int gcol = j0 + wn + tj * 16 + lr;
#pragma unroll
      for (int ti = 0; ti < 4; ++ti) {
        f32x4 v = acc[ti][tj];
#pragma unroll
        for (int r = 0; r < 4; ++r) {
          int grow = m0 + wm + ti * 16 + quad * 4 + r;
          if (gcol < 128)
            ((u16*)C0)[(size_t)grow * 128 + gcol] = f2b(v[r]);
          else
            ((float*)C1)[(size_t)grow * 128 + (gcol - 128)] = v[r];
        }
      }
    }
  }
}

// ---------------- GraphNorm: precompute affine, then apply+relu -------------

__global__ void k_precomp(const float* __restrict__ ssum, const float* __restrict__ ssq,
                          const float* __restrict__ inv_sz, const float* __restrict__ gw,
                          const float* __restrict__ gb, const float* __restrict__ alpha,
                          float* __restrict__ S, float* __restrict__ T) {
  int idx = blockIdx.x * blockDim.x + threadIdx.x;
  if (idx >= N_GROUPS * H_DIM) return;
  int g = idx >> 9;
  int c = idx & (H_DIM - 1);
  float is = inv_sz[g];
  float m = ssum[idx] * is;
  float a = alpha[c];
  float var = fmaxf(ssq[idx] * is - a * (2.f - a) * m * m, 0.f);
  float inv = rsqrtf(var + EPSV);
  float sc = inv * gw[c];
  S[idx] = sc;
  T[idx] = gb[c] - a * m * sc;
}

__global__ void k_apply(u16* __restrict__ h, const int* __restrict__ batch,
                        const float* __restrict__ S, const float* __restrict__ T) {
  int tid = blockIdx.x * blockDim.x + threadIdx.x;
  if (tid >= N_NODES * (H_DIM / 8)) return;
  int n = tid >> 6;
  int c0 = (tid & 63) << 3;
  int g = batch[n];
  u16x8 hv = *(const u16x8*)(h + (size_t)n * H_DIM + c0);
  u16x8 out;
#pragma unroll
  for (int j = 0; j < 8; ++j) {
    int f = c0 + j;
    float y = b2f(hv[j]) * S[g * H_DIM + f] + T[g * H_DIM + f];
    out[j] = f2b(fmaxf(y, 0.f));
  }
  *(u16x8*)(h + (size_t)n * H_DIM + c0) = out;
}

// ---------------- driver ----------------

extern "C" void kernel_launch(void* const* d_in, const int* in_sizes, int n_in,
                              void* d_out, int out_size, void* d_ws, size_t ws_size,
                              hipStream_t stream) {
  const float* x = (const float*)d_in[0];
  const int* edge = (const int*)d_in[1];
  const int* batch = (const int*)d_in[2];
  const float *Wl[5], *Wr[5], *bb[5];
  for (int i = 0; i < 5; ++i) {
    Wl[i] = (const float*)d_in[3 + 3 * i];
    Wr[i] = (const float*)d_in[4 + 3 * i];
    bb[i] = (const float*)d_in[5 + 3 * i];
  }
  const float *gamma[4], *beta[4], *alpha[4];
  for (int i = 0; i < 4; ++i) {
    gamma[i] = (const float*)d_in[18 + 3 * i];
    beta[i]  = (const float*)d_in[19 + 3 * i];
    alpha[i] = (const float*)d_in[20 + 3 * i];
  }
  const int* srcv = edge;
  const int* dstv = edge + N_EDGES;

  char* base = (char*)d_ws;
  size_t off = 0;
  auto carve = [&](size_t bytes) -> char* {
    char* p = base + off;
    off = (off + bytes + 255) & ~(size_t)255;
    return p;
  };
  int* deg       = (int*)carve((size_t)N_NODES * 4);
  float* inv_deg = (float*)carve((size_t)N_NODES * 4);
  int* csr_off   = (int*)carve((size_t)(N_NODES + 1) * 4);
  int* cursor    = (int*)carve((size_t)N_NODES * 4);
  int* csr_src   = (int*)carve((size_t)N_EDGES * 4);
  int* bsum      = (int*)carve((size_t)SCAN_NBLK * 4);
  int* gstart    = (int*)carve((size_t)(N_GROUPS + 1) * 4);
  float* inv_sz  = (float*)carve((size_t)N_GROUPS * 4);
  float* stats   = (float*)carve((size_t)4 * 2 * N_GROUPS * H_DIM * 4);
  float* Sbuf    = (float*)carve((size_t)N_GROUPS * H_DIM * 4);
  float* Tbuf    = (float*)carve((size_t)N_GROUPS * H_DIM * 4);
  u16* xb        = (u16*)carve((size_t)XB_EL * 2);
  u16* aggx      = (u16*)carve((size_t)XB_EL * 2);
  u16* h0        = (u16*)carve((size_t)M_PAD * H_DIM * 2);
  u16* h1        = (u16*)carve((size_t)M_PAD * H_DIM * 2);
  u16* h2        = (u16*)carve((size_t)M_PAD * H_DIM * 2);
  u16* wall      = (u16*)carve((size_t)WALL_EL * 2);
  (void)ws_size; (void)in_sizes; (void)n_in; (void)out_size;

  u16* w1lb = wall;
  u16* w1rb = wall + 32768;
  u16* w2lb = wall + 65536;
  u16* w2rb = wall + 327680;
  u16* w3lb = wall + 589824;
  u16* w3rb = wall + 851968;
  u16* w4lb = wall + 1114112;
  u16* w4rb = wall + 1376256;
  u16* w5cat = wall + 1638400;  // 256 x 512

  u16* Plb = h1;
  float* Prf = (float*)((char*)h1 + (size_t)M_PAD * 128 * 2);

  // graph preprocessing
  hipMemsetAsync(deg, 0, (size_t)N_NODES * 4, stream);
  k_deg<<<(N_EDGES + 255) / 256, 256, 0, stream>>>(dstv, deg);
  k_scan1<<<SCAN_NBLK, SCAN_BLK, 0, stream>>>(deg, csr_off, bsum);
  k_scan2_gbounds<<<2, 256, 0, stream>>>(bsum, batch, gstart, inv_sz);
  k_scan3prep<<<SCAN_NBLK, SCAN_BLK, 0, stream>>>(csr_off, bsum, deg, inv_deg, cursor);
  k_scatter<<<(N_EDGES + 255) / 256, 256, 0, stream>>>(srcv, dstv, cursor, csr_src);

  WcSrc ws_src;
  ws_src.p[0] = Wl[0]; ws_src.p[1] = Wr[0];
  ws_src.p[2] = Wl[1]; ws_src.p[3] = Wr[1];
  ws_src.p[4] = Wl[2]; ws_src.p[5] = Wr[2];
  ws_src.p[6] = Wl[3]; ws_src.p[7] = Wr[3];
  ws_src.p[8] = Wl[4]; ws_src.p[9] = Wr[4];
  k_convert_all<<<(XB_EL + WALL_EL + 255) / 256, 256, 0, stream>>>(x, ws_src, xb, wall);

  hipMemsetAsync(stats, 0, (size_t)4 * 2 * N_GROUPS * H_DIM * 4, stream);

  const int nblk_main = M_TILES * 4;  // JB=4
  const int nblk_l5   = M_TILES * 2;  // JB=2
  dim3 aggblk(64, 8);
  int aggrid = (N_NODES + 3) / 4;

  auto norm = [&](u16* h, int l) {
    float* ss = stats + (size_t)l * 2 * N_GROUPS * H_DIM;
    float* sq = ss + N_GROUPS * H_DIM;
    k_precomp<<<(N_GROUPS * H_DIM + 255) / 256, 256, 0, stream>>>(
        ss, sq, inv_sz, gamma[l], beta[l], alpha[l], Sbuf, Tbuf);
    k_apply<<<(N_NODES * (H_DIM / 8) + 255) / 256, 256, 0, stream>>>(
        h, batch, Sbuf, Tbuf);
  };
  auto stat_ptr = [&](int l) { return stats + (size_t)l * 2 * N_GROUPS * H_DIM; };

  // layer 1 (K = 64 padded)
  k_agg_small<<<N_NODES, 64, 0, stream>>>(xb, csr_off, csr_src, inv_deg, aggx);
  k_gemm_mfma<4, true, 0><<<nblk_main, 256, 0, stream>>>(
      aggx, xb, w1lb, w1rb, bb[0], h0, nullptr, batch,
      stat_ptr(0), stat_ptr(0) + N_GROUPS * H_DIM, K1PAD);
  norm(h0, 0);

  // layer 2
  k_agg512<<<aggrid, aggblk, 0, stream>>>(h0, csr_off, csr_src, inv_deg, h1);
  k_gemm_mfma<4, true, 0><<<nblk_main, 256, 0, stream>>>(
      h1, h0, w2lb, w2rb, bb[1], h2, nullptr, batch,
      stat_ptr(1), stat_ptr(1) + N_GROUPS * H_DIM, H_DIM);
  norm(h2, 1);

  // layer 3
  k_agg512<<<aggrid, aggblk, 0, stream>>>(h2, csr_off, csr_src, inv_deg, h0);
  k_gemm_mfma<4, true, 0><<<nblk_main, 256, 0, stream>>>(
      h0, h2, w3lb, w3rb, bb[2], h1, nullptr, batch,
      stat_ptr(2), stat_ptr(2) + N_GROUPS * H_DIM, H_DIM);
  norm(h1, 2);

  // layer 4
  k_agg512<<<aggrid, aggblk, 0, stream>>>(h1, csr_off, csr_src, inv_deg, h2);
  k_gemm_mfma<4, true, 0><<<nblk_main, 256, 0, stream>>>(
      h2, h1, w4lb, w4rb, bb[3], h0, nullptr, batch,
      stat_ptr(3), stat_ptr(3) + N_GROUPS * H_DIM, H_DIM);
  norm(h0, 3);

  // layer 5 via linearity: P = h0 @ [W5l|W5r]^T (J=256), then
  // out = inv_deg * segsum(Pl[src]) + Pr + b5
  k_gemm_mfma<2, false, 1><<<nblk_l5, 256, 0, stream>>>(
      h0, nullptr, w5cat, nullptr, nullptr, Plb, Prf, nullptr, nullptr, nullptr, H_DIM);
  k_agg_final<<<(N_NODES + 7) / 8, 256, 0, stream>>>(
      Plb, Prf, csr_off, csr_src, inv_deg, bb[4], (float*)d_out);
}

// Round 8
// 1075.018 us; speedup vs baseline: 4.4367x; 1.0125x over previous
//
#include <hip/hip_runtime.h>
#include <cstddef>
#include <cstdint>

#define N_NODES 50000
#define N_EDGES 800000
#define F_IN 50
#define K1PAD 64
#define H_DIM 512
#define O_DIM 121
#define N_GROUPS 20
#define EPSV 1e-5f
#define M_PAD 50048   // 391 * 128
#define M_TILES 391

#define SCAN_BLK 256
#define SCAN_NBLK ((N_NODES + SCAN_BLK - 1) / SCAN_BLK)  // 196
#define WALL_EL 1769472
#define XB_EL (M_PAD * K1PAD)

typedef unsigned short u16;
typedef __attribute__((ext_vector_type(8))) short short8;          // 8 bf16 (4 VGPRs)
typedef __attribute__((ext_vector_type(8))) unsigned short u16x8;  // 16B vector load
typedef __attribute__((ext_vector_type(4))) float f32x4;

__device__ __forceinline__ float b2f(u16 u) {
  union { unsigned int i; float f; } v; v.i = ((unsigned int)u) << 16; return v.f;
}
__device__ __forceinline__ u16 f2b(float f) {
  union { float f; unsigned int i; } v; v.f = f;
  unsigned int x = v.i;
  return (u16)((x + 0x7fffu + ((x >> 16) & 1u)) >> 16);  // RNE
}

__device__ __forceinline__ void gl_lds16(const void* g, void* l) {
  __builtin_amdgcn_global_load_lds(
      (__attribute__((address_space(1))) void*)(g),
      (__attribute__((address_space(3))) void*)(l), 16, 0, 0);
}

// ---------------- graph preprocessing ----------------

__global__ void k_deg(const int* __restrict__ dst, int* __restrict__ deg) {
  int e = blockIdx.x * blockDim.x + threadIdx.x;
  if (e < N_EDGES) atomicAdd(&deg[dst[e]], 1);
}

__global__ void k_scan1(const int* __restrict__ deg, int* __restrict__ off,
                        int* __restrict__ bsum) {
  __shared__ int buf[SCAN_BLK];
  int gid = blockIdx.x * SCAN_BLK + threadIdx.x;
  buf[threadIdx.x] = (gid < N_NODES) ? deg[gid] : 0;
  __syncthreads();
  for (int d = 1; d < SCAN_BLK; d <<= 1) {
    int t = (threadIdx.x >= d) ? buf[threadIdx.x - d] : 0;
    __syncthreads();
    buf[threadIdx.x] += t;
    __syncthreads();
  }
  if (gid < N_NODES) off[gid + 1] = buf[threadIdx.x];
  if (threadIdx.x == SCAN_BLK - 1) bsum[blockIdx.x] = buf[threadIdx.x];
}

// block 0: scan of block sums; block 1: group bounds from sorted batch
__global__ void k_scan2_gbounds(int* __restrict__ bsum, const int* __restrict__ batch,
                                int* __restrict__ gstart, float* __restrict__ inv_sz) {
  int t = threadIdx.x;
  if (blockIdx.x == 0) {
    __shared__ int buf[256];
    buf[t] = (t < SCAN_NBLK) ? bsum[t] : 0;
    __syncthreads();
    for (int d = 1; d < 256; d <<= 1) {
      int v = (t >= d) ? buf[t - d] : 0;
      __syncthreads();
      buf[t] += v;
      __syncthreads();
    }
    if (t < SCAN_NBLK) bsum[t] = buf[t];
  } else {
    if (t <= N_GROUPS) {
      int lo = 0, hi = N_NODES;
      while (lo < hi) {
        int mid = (lo + hi) >> 1;
        if (batch[mid] < t) lo = mid + 1; else hi = mid;
      }
      gstart[t] = lo;
    }
    __syncthreads();
    if (t < N_GROUPS) {
      int sz = gstart[t + 1] - gstart[t];
      inv_sz[t] = 1.0f / (float)max(sz, 1);
    }
  }
}

__global__ void k_scan3prep(int* __restrict__ off, const int* __restrict__ bsum,
                            const int* __restrict__ deg, float* __restrict__ inv_deg,
                            int* __restrict__ cursor) {
  int gid = blockIdx.x * SCAN_BLK + threadIdx.x;
  if (gid < N_NODES) {
    int add = (blockIdx.x > 0) ? bsum[blockIdx.x - 1] : 0;
    int v = off[gid + 1] + add;
    off[gid + 1] = v;
    if (gid + 1 < N_NODES) cursor[gid + 1] = v;
    inv_deg[gid] = 1.0f / (float)max(deg[gid], 1);
  }
  if (gid == 0) { off[0] = 0; cursor[0] = 0; }
}

__global__ void k_scatter(const int* __restrict__ src, const int* __restrict__ dst,
                          int* __restrict__ cursor, int* __restrict__ csr_src) {
  int e = blockIdx.x * blockDim.x + threadIdx.x;
  if (e < N_EDGES) {
    int p = atomicAdd(&cursor[dst[e]], 1);
    csr_src[p] = src[e];
  }
}

// ---------------- conversions (x pad + all weights, one launch) -------------
struct WcSrc { const float* p[10]; };
__global__ void k_convert_all(const float* __restrict__ x, WcSrc s,
                              u16* __restrict__ xb, u16* __restrict__ wall) {
  int idx = blockIdx.x * blockDim.x + threadIdx.x;
  if (idx < XB_EL) {
    int r = idx >> 6, c = idx & (K1PAD - 1);
    float v = (r < N_NODES && c < F_IN) ? x[r * F_IN + c] : 0.f;
    xb[idx] = f2b(v);
    return;
  }
  idx -= XB_EL;
  if (idx >= WALL_EL) return;
  const int seg_start[10] = {0, 32768, 65536, 327680, 589824, 851968,
                             1114112, 1376256, 1638400, 1703936};
  const int jr[10]  = {512, 512, 512, 512, 512, 512, 512, 512, 121, 121};
  const int kin[10] = {50, 50, 512, 512, 512, 512, 512, 512, 512, 512};
  const int ksh[10] = {6, 6, 9, 9, 9, 9, 9, 9, 9, 9};
  int sgi = 0;
#pragma unroll
  for (int t = 1; t < 10; ++t)
    if (idx >= seg_start[t]) sgi = t;
  int local = idx - seg_start[sgi];
  int j = local >> ksh[sgi];
  int k = local & ((1 << ksh[sgi]) - 1);
  float v = (j < jr[sgi] && k < kin[sgi]) ? s.p[sgi][j * kin[sgi] + k] : 0.f;
  wall[idx] = f2b(v);
}

// ---------------- aggregation ----------------

__global__ void k_agg_small(const u16* __restrict__ xb, const int* __restrict__ off,
                            const int* __restrict__ srcs, const float* __restrict__ inv_deg,
                            u16* __restrict__ agg) {
  int n = blockIdx.x;
  int f = threadIdx.x;  // 0..63
  int b = off[n], e = off[n + 1];
  float s = 0.f;
  for (int i = b; i < e; ++i) s += b2f(xb[(size_t)srcs[i] * K1PAD + f]);
  agg[(size_t)n * K1PAD + f] = f2b(s * inv_deg[n]);
}

// layers 2..4: 16B loads, 2 waves per node (edge split), 4 nodes per block.
// ~111 us: pinned at the L2-miss/L3 path ceiling for the random row gather
// (374 MB fetch of 819 MB logical) — occupancy/unroll variants all neutral.
__global__ __launch_bounds__(512) void k_agg512(
    const u16* __restrict__ h, const int* __restrict__ off,
    const int* __restrict__ srcs, const float* __restrict__ inv_deg,
    u16* __restrict__ agg) {
  __shared__ float part[4][64][8];  // 8 KB
  int slot = threadIdx.y >> 1;
  int sub = threadIdx.y & 1;
  int n = blockIdx.x * 4 + slot;
  int t = threadIdx.x;
  float a[8] = {0.f, 0.f, 0.f, 0.f, 0.f, 0.f, 0.f, 0.f};
  if (n < N_NODES) {
    int b = off[n], e = off[n + 1];
    int half = (e - b + 1) >> 1;
    int lo = b + sub * half;
    int hi = min(lo + half, e);
    int i = lo;
    for (; i + 4 <= hi; i += 4) {
      u16x8 v0 = ((const u16x8*)(h + (size_t)srcs[i + 0] * H_DIM))[t];
      u16x8 v1 = ((const u16x8*)(h + (size_t)srcs[i + 1] * H_DIM))[t];
      u16x8 v2 = ((const u16x8*)(h + (size_t)srcs[i + 2] * H_DIM))[t];
      u16x8 v3 = ((const u16x8*)(h + (size_t)srcs[i + 3] * H_DIM))[t];
#pragma unroll
      for (int j = 0; j < 8; ++j)
        a[j] += (b2f(v0[j]) + b2f(v1[j])) + (b2f(v2[j]) + b2f(v3[j]));
    }
    for (; i < hi; ++i) {
      u16x8 v0 = ((const u16x8*)(h + (size_t)srcs[i] * H_DIM))[t];
#pragma unroll
      for (int j = 0; j < 8; ++j) a[j] += b2f(v0[j]);
    }
  }
  if (sub == 1) {
#pragma unroll
    for (int j = 0; j < 8; ++j) part[slot][t][j] = a[j];
  }
  __syncthreads();
  if (sub == 0 && n < N_NODES) {
    float w = inv_deg[n];
    u16x8 r;
#pragma unroll
    for (int j = 0; j < 8; ++j) r[j] = f2b((a[j] + part[slot][t][j]) * w);
    ((u16x8*)(agg + (size_t)n * H_DIM))[t] = r;
  }
}

// layer 5 final: out[n] = inv_deg[n]*sum(Pl[src]) + Pr[n] + bias (121 cols)
__global__ __launch_bounds__(256) void k_agg_final(
    const u16* __restrict__ Plb, const float* __restrict__ Prf,
    const int* __restrict__ off, const int* __restrict__ srcs,
    const float* __restrict__ inv_deg, const float* __restrict__ bias,
    float* __restrict__ out) {
  int n = blockIdx.x * 8 + (threadIdx.x >> 5);
  if (n >= N_NODES) return;
  int l = threadIdx.x & 31;
  int c0 = l * 4;
  int b = off[n], e = off[n + 1];
  float a0 = 0.f, a1 = 0.f, a2 = 0.f, a3 = 0.f;
  int i = b;
  for (; i + 2 <= e; i += 2) {
    ushort4 v0 = ((const ushort4*)(Plb + (size_t)srcs[i] * 128))[l];
    ushort4 v1 = ((const ushort4*)(Plb + (size_t)srcs[i + 1] * 128))[l];
    a0 += b2f(v0.x) + b2f(v1.x); a1 += b2f(v0.y) + b2f(v1.y);
    a2 += b2f(v0.z) + b2f(v1.z); a3 += b2f(v0.w) + b2f(v1.w);
  }
  if (i < e) {
    ushort4 v0 = ((const ushort4*)(Plb + (size_t)srcs[i] * 128))[l];
    a0 += b2f(v0.x); a1 += b2f(v0.y); a2 += b2f(v0.z); a3 += b2f(v0.w);
  }
  float w = inv_deg[n];
  float4 pr = ((const float4*)(Prf + (size_t)n * 128))[l];
  float r0 = a0 * w + pr.x, r1 = a1 * w + pr.y;
  float r2 = a2 * w + pr.z, r3 = a3 * w + pr.w;
  size_t ob = (size_t)n * O_DIM;
  if (c0 + 0 < O_DIM) out[ob + c0 + 0] = r0 + bias[c0 + 0];
  if (c0 + 1 < O_DIM) out[ob + c0 + 1] = r1 + bias[c0 + 1];
  if (c0 + 2 < O_DIM) out[ob + c0 + 2] = r2 + bias[c0 + 2];
  if (c0 + 3 < O_DIM) out[ob + c0 + 3] = r3 + bias[c0 + 3];
}

// ---------------- MFMA GEMM ----------------
// DUAL(OUTMODE 0): C = A*Wl^T + X*Wr^T + b, bf16 out [*, 512]; GraphNorm
//   stats fused in epilogue. !DUAL(OUTMODE 1): P = A*Wl^T split bf16/f32.
// __launch_bounds__(256, 4): force <=128 regs/wave (acc 64 AGPR + 32 frag
//   + addressing) -> 4 waves/SIMD, attacks the barrier-drain stall with
//   more co-resident waves (was 144 regs -> 3 waves/SIMD, ~2 blocks/CU).

#define TM 128
#define TK 32

template <int JB, bool DUAL, int OUTMODE>
__global__ __launch_bounds__(256, 4) void k_gemm_mfma(
    const u16* __restrict__ A, const u16* __restrict__ X,
    const u16* __restrict__ Wl, const u16* __restrict__ Wr,
    const float* __restrict__ bias, void* __restrict__ C0,
    void* __restrict__ C1, const int* __restrict__ batch,
    float* __restrict__ ssum, float* __restrict__ ssq, int K) {
  __shared__ u16 As[TM * TK];
  __shared__ u16 Ls[TM * TK];
  __shared__ u16 Xs[DUAL ? TM * TK : 1];
  __shared__ u16 Rs[DUAL ? TM * TK : 1];

  int id = blockIdx.x;
  const int nfull = (M_TILES >> 3) * 8 * JB;
  int m_t, j_t;
  if (id < nfull) {
    m_t = (id / (8 * JB)) * 8 + (id & 7);
    j_t = (id >> 3) & (JB - 1);
  } else {
    int rem = id - nfull;
    const int nrem = M_TILES & 7;  // 7
    m_t = (M_TILES & ~7) + rem % nrem;
    j_t = rem / nrem;
  }
  int m0 = m_t * TM;
  int j0 = j_t * 128;

  int tid = threadIdx.x;
  int lane = tid & 63;
  int wave = tid >> 6;
  int quad = lane >> 4;
  int lr = lane & 15;
  int wm = (wave & 1) * 64;
  int wn = (wave >> 1) * 64;

  f32x4 acc[4][4] = {};

  int sr = tid >> 2;
  int sc = (tid & 3) * 8;
  size_t moff0 = (size_t)(m0 + sr) * K + sc;
  size_t moff1 = moff0 + (size_t)64 * K;
  size_t joff0 = (size_t)(j0 + sr) * K + sc;
  size_t joff1 = joff0 + (size_t)64 * K;
  const int dofs = tid * 8;

  for (int k0 = 0; k0 < K; k0 += TK) {
    __syncthreads();
    gl_lds16(A + moff0 + k0, As + dofs);
    gl_lds16(A + moff1 + k0, As + 2048 + dofs);
    gl_lds16(Wl + joff0 + k0, Ls + dofs);
    gl_lds16(Wl + joff1 + k0, Ls + 2048 + dofs);
    if constexpr (DUAL) {
      gl_lds16(X + moff0 + k0, Xs + dofs);
      gl_lds16(X + moff1 + k0, Xs + 2048 + dofs);
      gl_lds16(Wr + joff0 + k0, Rs + dofs);
      gl_lds16(Wr + joff1 + k0, Rs + 2048 + dofs);
    }
    __syncthreads();
    {
      short8 af[4], lf[4];
#pragma unroll
      for (int t = 0; t < 4; ++t) {
        af[t] = *(const short8*)(As + (wm + t * 16 + lr) * TK + quad * 8);
        lf[t] = *(const short8*)(Ls + (wn + t * 16 + lr) * TK + quad * 8);
      }
#pragma unroll
      for (int ti = 0; ti < 4; ++ti)
#pragma unroll
        for (int tj = 0; tj < 4; ++tj)
          acc[ti][tj] = __builtin_amdgcn_mfma_f32_16x16x32_bf16(
              af[ti], lf[tj], acc[ti][tj], 0, 0, 0);
    }
    if constexpr (DUAL) {
      short8 xf[4], rf[4];
#pragma unroll
      for (int t = 0; t < 4; ++t) {
        xf[t] = *(const short8*)(Xs + (wm + t * 16 + lr) * TK + quad * 8);
        rf[t] = *(const short8*)(Rs + (wn + t * 16 + lr) * TK + quad * 8);
      }
#pragma unroll
      for (int ti = 0; ti < 4; ++ti)
#pragma unroll
        for (int tj = 0; tj < 4; ++tj)
          acc[ti][tj] = __builtin_amdgcn_mfma_f32_16x16x32_bf16(
              xf[ti], rf[tj], acc[ti][tj], 0, 0, 0);
    }
  }

  // epilogue: C/D layout col=lane&15, row=quad*4+reg (m89-verified)
  if constexpr (OUTMODE == 0) {
    int glo = batch[m0];
    int lastrow = m0 + TM - 1;
    bool fast = (lastrow < N_NODES) && (batch[lastrow] == glo);
#pragma unroll
    for (int tj = 0; tj < 4; ++tj) {
      int gcol = j0 + wn + tj * 16 + lr;
      float bv = bias[gcol];
      float s = 0.f, q = 0.f;
#pragma unroll
      for (int ti = 0; ti < 4; ++ti) {
        f32x4 v = acc[ti][tj];
        int rbase = m0 + wm + ti * 16 + quad * 4;
        if (fast) {
#pragma unroll
          for (int r = 0; r < 4; ++r) {
            float val = v[r] + bv;
            ((u16*)C0)[(size_t)(rbase + r) * H_DIM + gcol] = f2b(val);
            s += val; q += val * val;
          }
        } else {
          if (rbase + 3 < N_NODES && batch[rbase] == batch[rbase + 3]) {
            float s4 = 0.f, q4 = 0.f;
#pragma unroll
            for (int r = 0; r < 4; ++r) {
              float val = v[r] + bv;
              ((u16*)C0)[(size_t)(rbase + r) * H_DIM + gcol] = f2b(val);
              s4 += val; q4 += val * val;
            }
            int g = batch[rbase];
            atomicAdd(&ssum[g * H_DIM + gcol], s4);
            atomicAdd(&ssq[g * H_DIM + gcol], q4);
          } else {
#pragma unroll
            for (int r = 0; r < 4; ++r) {
              int grow = rbase + r;
              if (grow < N_NODES) {
                float val = v[r] + bv;
                ((u16*)C0)[(size_t)grow * H_DIM + gcol] = f2b(val);
                int g = batch[grow];
                atomicAdd(&ssum[g * H_DIM + gcol], val);
                atomicAdd(&ssq[g * H_DIM + gcol], val * val);
              }
            }
          }
        }
      }
      if (fast) {
        s += __shfl_xor(s, 16); s += __shfl_xor(s, 32);
        q += __shfl_xor(q, 16); q += __shfl_xor(q, 32);
        if (quad == 0) {
          atomicAdd(&ssum[glo * H_DIM + gcol], s);
          atomicAdd(&ssq[glo * H_DIM + gcol], q);
        }
      }
    }
  } else {
#pragma unroll
    for (int tj = 0; tj < 4; ++tj) {
      int gcol = j0 + wn + tj * 16 + lr;
#pragma unroll
      for (int ti = 0; ti < 4; ++ti) {
        f32x4 v = acc[ti][tj];
#pragma unroll
        for (int r = 0; r < 4; ++r) {
          int grow = m0 + wm + ti * 16 + quad * 4 + r;
          if (gcol < 128)
            ((u16*)C0)[(size_t)grow * 128 + gcol] = f2b(v[r]);
          else
            ((float*)C1)[(size_t)grow * 128 + (gcol - 128)] = v[r];
        }
      }
    }
  }
}

// ---------------- GraphNorm: precompute affine, then apply+relu -------------

__global__ void k_precomp(const float* __restrict__ ssum, const float* __restrict__ ssq,
                          const float* __restrict__ inv_sz, const float* __restrict__ gw,
                          const float* __restrict__ gb, const float* __restrict__ alpha,
                          float* __restrict__ S, float* __restrict__ T) {
  int idx = blockIdx.x * blockDim.x + threadIdx.x;
  if (idx >= N_GROUPS * H_DIM) return;
  int g = idx >> 9;
  int c = idx & (H_DIM - 1);
  float is = inv_sz[g];
  float m = ssum[idx] * is;
  float a = alpha[c];
  float var = fmaxf(ssq[idx] * is - a * (2.f - a) * m * m, 0.f);
  float inv = rsqrtf(var + EPSV);
  float sc = inv * gw[c];
  S[idx] = sc;
  T[idx] = gb[c] - a * m * sc;
}

__global__ void k_apply(u16* __restrict__ h, const int* __restrict__ batch,
                        const float* __restrict__ S, const float* __restrict__ T) {
  int tid = blockIdx.x * blockDim.x + threadIdx.x;
  if (tid >= N_NODES * (H_DIM / 8)) return;
  int n = tid >> 6;
  int c0 = (tid & 63) << 3;
  int g = batch[n];
  u16x8 hv = *(const u16x8*)(h + (size_t)n * H_DIM + c0);
  u16x8 out;
#pragma unroll
  for (int j = 0; j < 8; ++j) {
    int f = c0 + j;
    float y = b2f(hv[j]) * S[g * H_DIM + f] + T[g * H_DIM + f];
    out[j] = f2b(fmaxf(y, 0.f));
  }
  *(u16x8*)(h + (size_t)n * H_DIM + c0) = out;
}

// ---------------- driver ----------------

extern "C" void kernel_launch(void* const* d_in, const int* in_sizes, int n_in,
                              void* d_out, int out_size, void* d_ws, size_t ws_size,
                              hipStream_t stream) {
  const float* x = (const float*)d_in[0];
  const int* edge = (const int*)d_in[1];
  const int* batch = (const int*)d_in[2];
  const float *Wl[5], *Wr[5], *bb[5];
  for (int i = 0; i < 5; ++i) {
    Wl[i] = (const float*)d_in[3 + 3 * i];
    Wr[i] = (const float*)d_in[4 + 3 * i];
    bb[i] = (const float*)d_in[5 + 3 * i];
  }
  const float *gamma[4], *beta[4], *alpha[4];
  for (int i = 0; i < 4; ++i) {
    gamma[i] = (const float*)d_in[18 + 3 * i];
    beta[i]  = (const float*)d_in[19 + 3 * i];
    alpha[i] = (const float*)d_in[20 + 3 * i];
  }
  const int* srcv = edge;
  const int* dstv = edge + N_EDGES;

  char* base = (char*)d_ws;
  size_t off = 0;
  auto carve = [&](size_t bytes) -> char* {
    char* p = base + off;
    off = (off + bytes + 255) & ~(size_t)255;
    return p;
  };
  int* deg       = (int*)carve((size_t)N_NODES * 4);
  float* inv_deg = (float*)carve((size_t)N_NODES * 4);
  int* csr_off   = (int*)carve((size_t)(N_NODES + 1) * 4);
  int* cursor    = (int*)carve((size_t)N_NODES * 4);
  int* csr_src   = (int*)carve((size_t)N_EDGES * 4);
  int* bsum      = (int*)carve((size_t)SCAN_NBLK * 4);
  int* gstart    = (int*)carve((size_t)(N_GROUPS + 1) * 4);
  float* inv_sz  = (float*)carve((size_t)N_GROUPS * 4);
  float* stats   = (float*)carve((size_t)4 * 2 * N_GROUPS * H_DIM * 4);
  float* Sbuf    = (float*)carve((size_t)N_GROUPS * H_DIM * 4);
  float* Tbuf    = (float*)carve((size_t)N_GROUPS * H_DIM * 4);
  u16* xb        = (u16*)carve((size_t)XB_EL * 2);
  u16* aggx      = (u16*)carve((size_t)XB_EL * 2);
  u16* h0        = (u16*)carve((size_t)M_PAD * H_DIM * 2);
  u16* h1        = (u16*)carve((size_t)M_PAD * H_DIM * 2);
  u16* h2        = (u16*)carve((size_t)M_PAD * H_DIM * 2);
  u16* wall      = (u16*)carve((size_t)WALL_EL * 2);
  (void)ws_size; (void)in_sizes; (void)n_in; (void)out_size;

  u16* w1lb = wall;
  u16* w1rb = wall + 32768;
  u16* w2lb = wall + 65536;
  u16* w2rb = wall + 327680;
  u16* w3lb = wall + 589824;
  u16* w3rb = wall + 851968;
  u16* w4lb = wall + 1114112;
  u16* w4rb = wall + 1376256;
  u16* w5cat = wall + 1638400;  // 256 x 512

  u16* Plb = h1;
  float* Prf = (float*)((char*)h1 + (size_t)M_PAD * 128 * 2);

  // graph preprocessing
  hipMemsetAsync(deg, 0, (size_t)N_NODES * 4, stream);
  k_deg<<<(N_EDGES + 255) / 256, 256, 0, stream>>>(dstv, deg);
  k_scan1<<<SCAN_NBLK, SCAN_BLK, 0, stream>>>(deg, csr_off, bsum);
  k_scan2_gbounds<<<2, 256, 0, stream>>>(bsum, batch, gstart, inv_sz);
  k_scan3prep<<<SCAN_NBLK, SCAN_BLK, 0, stream>>>(csr_off, bsum, deg, inv_deg, cursor);
  k_scatter<<<(N_EDGES + 255) / 256, 256, 0, stream>>>(srcv, dstv, cursor, csr_src);

  WcSrc ws_src;
  ws_src.p[0] = Wl[0]; ws_src.p[1] = Wr[0];
  ws_src.p[2] = Wl[1]; ws_src.p[3] = Wr[1];
  ws_src.p[4] = Wl[2]; ws_src.p[5] = Wr[2];
  ws_src.p[6] = Wl[3]; ws_src.p[7] = Wr[3];
  ws_src.p[8] = Wl[4]; ws_src.p[9] = Wr[4];
  k_convert_all<<<(XB_EL + WALL_EL + 255) / 256, 256, 0, stream>>>(x, ws_src, xb, wall);

  hipMemsetAsync(stats, 0, (size_t)4 * 2 * N_GROUPS * H_DIM * 4, stream);

  const int nblk_main = M_TILES * 4;  // JB=4
  const int nblk_l5   = M_TILES * 2;  // JB=2
  dim3 aggblk(64, 8);
  int aggrid = (N_NODES + 3) / 4;

  auto norm = [&](u16* h, int l) {
    float* ss = stats + (size_t)l * 2 * N_GROUPS * H_DIM;
    float* sq = ss + N_GROUPS * H_DIM;
    k_precomp<<<(N_GROUPS * H_DIM + 255) / 256, 256, 0, stream>>>(
        ss, sq, inv_sz, gamma[l], beta[l], alpha[l], Sbuf, Tbuf);
    k_apply<<<(N_NODES * (H_DIM / 8) + 255) / 256, 256, 0, stream>>>(
        h, batch, Sbuf, Tbuf);
  };
  auto stat_ptr = [&](int l) { return stats + (size_t)l * 2 * N_GROUPS * H_DIM; };

  // layer 1 (K = 64 padded)
  k_agg_small<<<N_NODES, 64, 0, stream>>>(xb, csr_off, csr_src, inv_deg, aggx);
  k_gemm_mfma<4, true, 0><<<nblk_main, 256, 0, stream>>>(
      aggx, xb, w1lb, w1rb, bb[0], h0, nullptr, batch,
      stat_ptr(0), stat_ptr(0) + N_GROUPS * H_DIM, K1PAD);
  norm(h0, 0);

  // layer 2
  k_agg512<<<aggrid, aggblk, 0, stream>>>(h0, csr_off, csr_src, inv_deg, h1);
  k_gemm_mfma<4, true, 0><<<nblk_main, 256, 0, stream>>>(
      h1, h0, w2lb, w2rb, bb[1], h2, nullptr, batch,
      stat_ptr(1), stat_ptr(1) + N_GROUPS * H_DIM, H_DIM);
  norm(h2, 1);

  // layer 3
  k_agg512<<<aggrid, aggblk, 0, stream>>>(h2, csr_off, csr_src, inv_deg, h0);
  k_gemm_mfma<4, true, 0><<<nblk_main, 256, 0, stream>>>(
      h0, h2, w3lb, w3rb, bb[2], h1, nullptr, batch,
      stat_ptr(2), stat_ptr(2) + N_GROUPS * H_DIM, H_DIM);
  norm(h1, 2);

  // layer 4
  k_agg512<<<aggrid, aggblk, 0, stream>>>(h1, csr_off, csr_src, inv_deg, h2);
  k_gemm_mfma<4, true, 0><<<nblk_main, 256, 0, stream>>>(
      h2, h1, w4lb, w4rb, bb[3], h0, nullptr, batch,
      stat_ptr(3), stat_ptr(3) + N_GROUPS * H_DIM, H_DIM);
  norm(h0, 3);

  // layer 5 via linearity: P = h0 @ [W5l|W5r]^T (J=256), then
  // out = inv_deg * segsum(Pl[src]) + Pr + b5
  k_gemm_mfma<2, false, 1><<<nblk_l5, 256, 0, stream>>>(
      h0, nullptr, w5cat, nullptr, nullptr, Plb, Prf, nullptr, nullptr, nullptr, H_DIM);
  k_agg_final<<<(N_NODES + 7) / 8, 256, 0, stream>>>(
      Plb, Prf, csr_off, csr_src, inv_deg, bb[4], (float*)d_out);
}